// Round 3
// baseline (805.659 us; speedup 1.0000x reference)
//
#include <hip/hip_runtime.h>
#include <hip/hip_bf16.h>

// Problem constants
#define HID   2560
#define NH    32
#define HD    80      // head dim
#define SEQ   2048
#define TTOT  4096    // B*S
#define QKVN  7680    // 3*HID

typedef float  f32x4  __attribute__((ext_vector_type(4)));
typedef short  short8 __attribute__((ext_vector_type(8)));
typedef __bf16 bf16x8 __attribute__((ext_vector_type(8)));
typedef __hip_bfloat16 bf16;

__device__ __forceinline__ float bf2f(bf16 h) { return __bfloat162float(h); }
__device__ __forceinline__ bf16  f2bf(float f) { return __float2bfloat16(f); }

__device__ __forceinline__ f32x4 mfma16(short8 a, short8 b, f32x4 c) {
  return __builtin_amdgcn_mfma_f32_16x16x32_bf16(
      __builtin_bit_cast(bf16x8, a), __builtin_bit_cast(bf16x8, b), c, 0, 0, 0);
}

// async global->LDS, 16B per lane: LDS dest = wave-uniform base + lane*16,
// global side is a per-lane gather.
typedef __attribute__((address_space(1))) const unsigned int as1_uint;
typedef __attribute__((address_space(3))) unsigned int       as3_uint;
__device__ __forceinline__ void gld16(const void* g, void* l) {
  __builtin_amdgcn_global_load_lds((as1_uint*)g, (as3_uint*)l, 16, 0, 0);
}

// ---------------------------------------------------------------------------
// Dtype detection (flag=1 -> inputs are f32; 0 -> bf16).
// ---------------------------------------------------------------------------
__global__ void detect_kernel(const unsigned short* __restrict__ hid, int* flag) {
  const int tid = threadIdx.x;  // 256
  const unsigned short u = hid[2 * (tid * 997)];
  const int e = (u >> 7) & 0xFF;
  const int sane = (u == 0 || (e >= 0x60 && e <= 0x8A)) ? 1 : 0;
  __shared__ int cnt;
  if (tid == 0) cnt = 0;
  __syncthreads();
  atomicAdd(&cnt, sane);
  __syncthreads();
  if (tid == 0) *flag = (cnt < 160) ? 1 : 0;
}

// Normalize float input to bf16, 8 elems/thread. n8 = n/8.
__global__ void convert_kernel(const void* __restrict__ src, bf16* __restrict__ dst,
                               int n8, const int* __restrict__ flag) {
  const bool isf32 = (*flag != 0);
  for (int i = blockIdx.x * 256 + threadIdx.x; i < n8; i += gridDim.x * 256) {
    if (isf32) {
      const float4* s = (const float4*)src;
      float4 a = s[2 * i], b = s[2 * i + 1];
      __align__(16) bf16 o8[8] = {f2bf(a.x), f2bf(a.y), f2bf(a.z), f2bf(a.w),
                                  f2bf(b.x), f2bf(b.y), f2bf(b.z), f2bf(b.w)};
      *(uint4*)(dst + 8 * i) = *(const uint4*)o8;
    } else {
      *(uint4*)(dst + 8 * i) = ((const uint4*)src)[i];
    }
  }
}

// Emit output in true dtype. n8 = n/8.
__global__ void emit_kernel(const bf16* __restrict__ src, void* __restrict__ dst,
                            int n8, const int* __restrict__ flag) {
  const bool isf32 = (*flag != 0);
  for (int i = blockIdx.x * 256 + threadIdx.x; i < n8; i += gridDim.x * 256) {
    uint4 v = *(const uint4*)(src + 8 * i);
    if (isf32) {
      const bf16* b = (const bf16*)&v;
      float4* d = (float4*)dst;
      d[2 * i]     = make_float4(bf2f(b[0]), bf2f(b[1]), bf2f(b[2]), bf2f(b[3]));
      d[2 * i + 1] = make_float4(bf2f(b[4]), bf2f(b[5]), bf2f(b[6]), bf2f(b[7]));
    } else {
      ((uint4*)dst)[i] = v;
    }
  }
}

// ---------------------------------------------------------------------------
// GEMM, 256x256 tile / BK=64 / 8 waves. 4-phase schedule with REGISTER-LEVEL
// SOFTWARE PIPELINING: every ds_read batch is issued one phase ahead of its
// MFMA consumer and waited with a COUNTED lgkmcnt (never 0 in steady state),
// so the LDS pipe drains underneath the MFMA clusters instead of serializing
// with them (round-2 counters: LDS 2313cy + MFMA 2061cy were additive).
//
//   ph1: issue b23 (+4)            ; lgkm(4)  ; MFMA a03 x b01   (acc[0..3][0..1])
//   ph2: issue a47 (+8)            ; lgkm(8)  ; MFMA a03 x b23   (acc[0..3][2..3])
//   ph3: vmcnt(4); barrier; stageB0; issue next-tile a03',b01' (+12)
//                                  ; lgkm(12) ; MFMA a47 x b23   (acc[4..7][2..3])
//   ph4: barrier; stageB1          ; (no wait); MFMA a47 x b01   (acc[4..7][0..1])
//
// b01 is the only frag set live across the reload point -> ping-pong b01A/b01B
// (static indexing) via 2x-unrolled tile loop. A triple-buffered, B double-
// buffered (160 KiB LDS), depth-2 staging: A[t+2] in ph1/2, B[t+2] in ph3/4.
// vmcnt(4) at ph3 = drain A[t+1],B[t+1] (issued tile t-1), leave A[t+2].
// Barriers: 2/K-tile (ph3: B WAR + staging visibility; ph4: A WAR).
// Requires M%256==0, N%256==0, K%64==0.
//
// LDS swizzle: phys_byte = logical_byte ^ ((row&7)<<4) applied on the global
// source at stage time + on the ds_read address (both-sides involution).
// ---------------------------------------------------------------------------
__global__ __launch_bounds__(512, 2) void gemm256_bias(
    const bf16* __restrict__ A, const bf16* __restrict__ B,
    const bf16* __restrict__ bias, bf16* __restrict__ C,
    int M, int N, int K)
{
  __shared__ __align__(16) bf16 lA[3][16384];   // 3 x 256rows x 64cols
  __shared__ __align__(16) bf16 lB[2][16384];   // 2 x 256rows x 64cols

  const int tid  = threadIdx.x;
  const int wid  = tid >> 6;
  const int lane = tid & 63;
  const int quad = lane >> 4;
  const int l15  = lane & 15;
  const int wr   = wid >> 2;   // 0..1 -> 128 rows each
  const int wc   = wid & 3;    // 0..3 -> 64 cols each

  // bijective XCD-aware block swizzle (m204)
  int wgid;
  {
    const int nwg = gridDim.x;
    const int q = nwg >> 3, r = nwg & 7;
    const int xcd = blockIdx.x & 7, lin = blockIdx.x >> 3;
    wgid = (xcd < r ? xcd * (q + 1) : r * (q + 1) + (xcd - r) * q) + lin;
  }
  const int gx = M >> 8;
  const int m0 = (wgid % gx) << 8;
  const int n0 = (wgid / gx) << 8;

  const int NT = K >> 6;   // K-tiles of 64

  // Staging geometry: half-tile = 128 rows x 64 cols = 1024 chunks of 16B.
  // Thread handles phys chunks tid and tid+512 (same swizzled col, +64 rows).
  const int rr   = tid >> 3;                               // phys row 0..63
  const int cbyt = ((tid & 7) << 4) ^ ((rr & 7) << 4);     // logical col byte
  const size_t o1 = (size_t)rr * K + (cbyt >> 1);
  const size_t o2 = o1 + (size_t)64 * K;

  const bf16* Ab = A + (size_t)m0 * K;
  const bf16* Bb = B + (size_t)n0 * K;

#define STAGEA(bufsel, half, tt)                                               \
  {                                                                            \
    const bf16* _s = Ab + (size_t)(half) * 128 * K + (size_t)(tt) * 64;        \
    bf16* _d = &lA[bufsel][(half) * 8192 + wid * 512];                         \
    gld16(_s + o1, _d);                                                        \
    gld16(_s + o2, _d + 4096);                                                 \
  }
#define STAGEB(bufsel, half, tt)                                               \
  {                                                                            \
    const bf16* _s = Bb + (size_t)(half) * 128 * K + (size_t)(tt) * 64;        \
    bf16* _d = &lB[bufsel][(half) * 8192 + wid * 512];                         \
    gld16(_s + o1, _d);                                                        \
    gld16(_s + o2, _d + 4096);                                                 \
  }

#define WAIT_LGKM(n)                                                           \
  do {                                                                         \
    asm volatile("s_waitcnt lgkmcnt(" #n ")" ::: "memory");                    \
    __builtin_amdgcn_sched_barrier(0);                                         \
  } while (0)
#define WAIT_VM(n) asm volatile("s_waitcnt vmcnt(" #n ")" ::: "memory")

  // frag-read swizzled 16B-column offsets (bytes) for ks=0,1
  const int csw0 = ((quad ^ (l15 & 7)) << 4);
  const int csw1 = (((4 | quad) ^ (l15 & 7)) << 4);

  f32x4 acc[8][4];
#pragma unroll
  for (int i = 0; i < 8; ++i)
#pragma unroll
    for (int j = 0; j < 4; ++j) acc[i][j] = (f32x4)0.f;

  short8 a03[4][2], a47[4][2], b23[2][2], b01A[2][2], b01B[2][2];

  // Prologue: stage tiles 0,1 in full; wait tile0; pre-issue tile0's a03,b01.
  STAGEA(0, 0, 0); STAGEA(0, 1, 0);
  STAGEB(0, 0, 0); STAGEB(0, 1, 0);
  if (NT > 1) {
    STAGEA(1, 0, 1); STAGEA(1, 1, 1);
    STAGEB(1, 0, 1); STAGEB(1, 1, 1);
    WAIT_VM(8);                        // tile0's 8 loads landed
  } else {
    WAIT_VM(0);
  }
  __builtin_amdgcn_s_barrier();
#pragma unroll
  for (int mi = 0; mi < 4; ++mi) {
    const char* p = (const char*)lA[0] + (size_t)(wr * 128 + mi * 16 + l15) * 128;
    a03[mi][0] = *(const short8*)(p + csw0);
    a03[mi][1] = *(const short8*)(p + csw1);
  }
#pragma unroll
  for (int n = 0; n < 2; ++n) {
    const char* p = (const char*)lB[0] + (size_t)(wc * 64 + n * 16 + l15) * 128;
    b01A[n][0] = *(const short8*)(p + csw0);
    b01A[n][1] = *(const short8*)(p + csw1);
  }
  // 12 ds_reads in flight entering the loop (steady-state invariant).

#define KTILE(T, B01U, B01L)                                                   \
  do {                                                                         \
    const int _t = (T);                                                        \
    const bf16* Al = lA[_t % 3];                                               \
    const bf16* Bl = lB[_t & 1];                                               \
    const bool stg = (_t + 2 < NT);                                            \
    const bool nxt = (_t + 1 < NT);                                            \
    /* ---- ph1: stage Ah0[t+2]; issue b23; wait cross-tile 12; MFMA lo x b01 */ \
    if (stg) STAGEA((_t + 2) % 3, 0, _t + 2);                                  \
    _Pragma("unroll") for (int n = 0; n < 2; ++n) {                            \
      const char* p = (const char*)Bl + (size_t)(wc * 64 + (2 + n) * 16 + l15) * 128; \
      b23[n][0] = *(const short8*)(p + csw0);                                  \
      b23[n][1] = *(const short8*)(p + csw1);                                  \
    }                                                                          \
    WAIT_LGKM(4);                                                              \
    __builtin_amdgcn_s_setprio(1);                                             \
    _Pragma("unroll") for (int mi = 0; mi < 4; ++mi)                           \
      _Pragma("unroll") for (int n = 0; n < 2; ++n) {                          \
        acc[mi][n] = mfma16(a03[mi][0], B01U[n][0], acc[mi][n]);               \
        acc[mi][n] = mfma16(a03[mi][1], B01U[n][1], acc[mi][n]);               \
      }                                                                        \
    __builtin_amdgcn_s_setprio(0);                                             \
    /* ---- ph2: stage Ah1[t+2]; issue a47; wait b23; MFMA lo x b23 */         \
    if (stg) STAGEA((_t + 2) % 3, 1, _t + 2);                                  \
    _Pragma("unroll") for (int mi = 0; mi < 4; ++mi) {                         \
      const char* p = (const char*)Al + (size_t)(wr * 128 + 64 + mi * 16 + l15) * 128; \
      a47[mi][0] = *(const short8*)(p + csw0);                                 \
      a47[mi][1] = *(const short8*)(p + csw1);                                 \
    }                                                                          \
    WAIT_LGKM(8);                                                              \
    __builtin_amdgcn_s_setprio(1);                                             \
    _Pragma("unroll") for (int mi = 0; mi < 4; ++mi)                           \
      _Pragma("unroll") for (int n = 0; n < 2; ++n) {                          \
        acc[mi][2 + n] = mfma16(a03[mi][0], b23[n][0], acc[mi][2 + n]);        \
        acc[mi][2 + n] = mfma16(a03[mi][1], b23[n][1], acc[mi][2 + n]);        \
      }                                                                        \
    __builtin_amdgcn_s_setprio(0);                                             \
    /* ---- ph3: vmcnt ckpt + barrier; stage Bh0[t+2]; issue next a03',b01';   \
            wait a47; MFMA hi x b23 */                                         \
    if (stg) { WAIT_VM(4); } else { WAIT_VM(0); }                              \
    __builtin_amdgcn_s_barrier();                                              \
    if (stg) STAGEB(_t & 1, 0, _t + 2);                                        \
    if (nxt) {                                                                 \
      const bf16* Aln = lA[(_t + 1) % 3];                                      \
      const bf16* Bln = lB[(_t + 1) & 1];                                      \
      _Pragma("unroll") for (int mi = 0; mi < 4; ++mi) {                       \
        const char* p = (const char*)Aln + (size_t)(wr * 128 + mi * 16 + l15) * 128; \
        a03[mi][0] = *(const short8*)(p + csw0);                               \
        a03[mi][1] = *(const short8*)(p + csw1);                               \
      }                                                                        \
      _Pragma("unroll") for (int n = 0; n < 2; ++n) {                          \
        const char* p = (const char*)Bln + (size_t)(wc * 64 + n * 16 + l15) * 128; \
        B01L[n][0] = *(const short8*)(p + csw0);                               \
        B01L[n][1] = *(const short8*)(p + csw1);                               \
      }                                                                        \
      WAIT_LGKM(12);                                                           \
    } else {                                                                   \
      WAIT_LGKM(0);                                                            \
    }                                                                          \
    __builtin_amdgcn_s_setprio(1);                                             \
    _Pragma("unroll") for (int mi = 0; mi < 4; ++mi)                           \
      _Pragma("unroll") for (int n = 0; n < 2; ++n) {                          \
        acc[4 + mi][2 + n] = mfma16(a47[mi][0], b23[n][0], acc[4 + mi][2 + n]); \
        acc[4 + mi][2 + n] = mfma16(a47[mi][1], b23[n][1], acc[4 + mi][2 + n]); \
      }                                                                        \
    __builtin_amdgcn_s_setprio(0);                                             \
    /* ---- ph4: barrier (A WAR); stage Bh1[t+2]; MFMA hi x b01 (reg-only) */  \
    __builtin_amdgcn_s_barrier();                                              \
    if (stg) STAGEB(_t & 1, 1, _t + 2);                                        \
    __builtin_amdgcn_s_setprio(1);                                             \
    _Pragma("unroll") for (int mi = 0; mi < 4; ++mi)                           \
      _Pragma("unroll") for (int n = 0; n < 2; ++n) {                          \
        acc[4 + mi][n] = mfma16(a47[mi][0], B01U[n][0], acc[4 + mi][n]);       \
        acc[4 + mi][n] = mfma16(a47[mi][1], B01U[n][1], acc[4 + mi][n]);       \
      }                                                                        \
    __builtin_amdgcn_s_setprio(0);                                             \
  } while (0)

  for (int t = 0; t < NT; t += 2) {
    KTILE(t, b01A, b01B);
    if (t + 1 < NT) KTILE(t + 1, b01B, b01A);
  }
#undef KTILE
#undef STAGEA
#undef STAGEB
#undef WAIT_LGKM
#undef WAIT_VM

  // Epilogue: C += bias
  const int crow = m0 + wr * 128 + quad * 4;
  const int ccol = n0 + wc * 64 + l15;
#pragma unroll
  for (int n = 0; n < 4; ++n) {
    const float bv = bf2f(bias[ccol + n * 16]);
#pragma unroll
    for (int mi = 0; mi < 8; ++mi) {
      const int rb = crow + mi * 16;
#pragma unroll
      for (int r = 0; r < 4; ++r)
        C[(size_t)(rb + r) * N + ccol + n * 16] = f2bf(acc[mi][n][r] + bv);
    }
  }
}

// ---------------------------------------------------------------------------
// RoPE + repack: qkv[t][7680] -> Qr/Kr [bh][s][80]; Q pre-scaled by 1/sqrt(80)
// ---------------------------------------------------------------------------
__global__ __launch_bounds__(256) void rope_kernel(
    const bf16* __restrict__ qkv, const bf16* __restrict__ cosb,
    const bf16* __restrict__ sinb, bf16* __restrict__ Qr, bf16* __restrict__ Kr)
{
  const int t = blockIdx.x;
  const int b = t >> 11;
  const int s = t & 2047;
  const float qscale = 0.11180339887498949f;

  __shared__ float cs[20], sn[20];
  if (threadIdx.x < 20) cs[threadIdx.x] = bf2f(cosb[t * 20 + threadIdx.x]);
  if (threadIdx.x >= 32 && threadIdx.x < 52)
    sn[threadIdx.x - 32] = bf2f(sinb[t * 20 + (threadIdx.x - 32)]);
  __syncthreads();

  const bf16* qrow = qkv + (size_t)t * QKVN;
  const bf16* krow = qrow + HID;

  for (int idx = threadIdx.x; idx < HID; idx += 256) {
    const int h = idx / HD, d = idx % HD;
    const size_t off = ((size_t)(b * NH + h) * SEQ + s) * HD + d;
    float q, k;
    if (d < 20) {
      q = bf2f(qrow[h * HD + d]) * cs[d] - bf2f(qrow[h * HD + d + 20]) * sn[d];
      k = bf2f(krow[h * HD + d]) * cs[d] - bf2f(krow[h * HD + d + 20]) * sn[d];
    } else if (d < 40) {
      q = bf2f(qrow[h * HD + d - 20]) * sn[d - 20] + bf2f(qrow[h * HD + d]) * cs[d - 20];
      k = bf2f(krow[h * HD + d - 20]) * sn[d - 20] + bf2f(krow[h * HD + d]) * cs[d - 20];
    } else {
      q = bf2f(qrow[h * HD + d]);
      k = bf2f(krow[h * HD + d]);
    }
    Qr[off] = f2bf(q * qscale);
    Kr[off] = f2bf(k);
  }
}

// ---------------------------------------------------------------------------
// V transpose: qkv V-part [t][h*80+d] -> Vt [bh][d][s]
// ---------------------------------------------------------------------------
__global__ __launch_bounds__(256) void vtrans_kernel(
    const bf16* __restrict__ qkv, bf16* __restrict__ Vt)
{
  const int bh = blockIdx.x;
  const int s0 = blockIdx.y * 64;
  const int b = bh >> 5, h = bh & 31;
  __shared__ bf16 tile[64][81];

  for (int e = threadIdx.x; e < 64 * HD; e += 256) {
    const int r = e / HD, d = e % HD;
    tile[r][d] = qkv[(size_t)(b * SEQ + s0 + r) * QKVN + 2 * HID + h * HD + d];
  }
  __syncthreads();
  for (int e = threadIdx.x; e < 64 * HD; e += 256) {
    const int d = e >> 6, r = e & 63;
    Vt[((size_t)bh * HD + d) * SEQ + s0 + r] = tile[r][d];
  }
}

// ---------------------------------------------------------------------------
// Flash attention v4, causal. Block = 128 q-rows (4 waves x 2 frags of 16),
// kv-step 64. Staging via global_load_lds (1424 contiguous 16B chunks: K tile
// [64][88] + V tile rows 0..79 of [96][72]); V rows 80..95 = ones (denominator
// accumulated as PV's 6th d-tile). QK^T computed TRANSPOSED (K as A-operand,
// Q as B-operand -> S^T C-layout: kv=quad*4+r, qrow=l15) so softmax rows are
// per-lane and P^T is written with packed b64 stores straight into A-layout.
// ---------------------------------------------------------------------------
__global__ __launch_bounds__(256, 3) void attn_kernel(
    const bf16* __restrict__ Qr, const bf16* __restrict__ Kr,
    const bf16* __restrict__ Vt, bf16* __restrict__ O)
{
  // XCD-aware decode: 16 q-blocks of a bh share an XCD; heavy qblk first
  const int raw  = blockIdx.x;          // 0..1023
  const int slot = raw >> 3;
  const int qblk = 15 - (slot & 15);
  const int bh   = ((slot >> 4) << 3) + (raw & 7);

  const int tid  = threadIdx.x;
  const int wave = tid >> 6;
  const int lane = tid & 63;
  const int quad = lane >> 4;
  const int l15  = lane & 15;
  const int qbase = qblk * 128;

  // staging region: 1424 chunks *16B = kt[64][88] then vt rows 0..79 of [96][72]
  // (kt col-pad 80..87 and vt col-pad 64..71 are garbage chunks, never read
  //  or killed by zero operands); vt rows 80..95 = ones, init'd once.
  __shared__ __align__(16) bf16 stage[12544];
  __shared__ __align__(16) bf16 pt[4 * 2 * 1152];   // per wave x frag: [16][72] P^T

  bf16* kt = stage;            // 64*88
  bf16* vt = stage + 5632;     // 96*72

  if (tid < 144) {
    const unsigned one2 = 0x3F803F80u;  // two bf16 1.0
    *(uint4*)&vt[5760 + tid * 8] = (uint4){one2, one2, one2, one2};
  }

  // staging chunk -> static global byte offset (c==pad chunk -> row start)
  int goff[6];
#pragma unroll
  for (int it = 0; it < 6; it++) {
    const int j = tid + it * 256;
    if (j < 704) {                       // K: row r (160B) as 10 chunks + 1 pad
      const int r = j / 11; int c = j - 11 * r; if (c > 9) c = 0;
      goff[it] = r * 160 + c * 16;
    } else {                             // V: row r (128B) as 8 chunks + 1 pad
      const int j2 = j - 704;
      const int r = j2 / 9; int c = j2 - 9 * r; if (c > 7) c = 0;
      goff[it] = r * 4096 + c * 16;
    }
  }

  // Q fragments: 2 frags x 3 K-chunks, resident (scale pre-folded at RoPE)
  short8 aq[2][3];
#pragma unroll
  for (int f = 0; f < 2; f++) {
    const bf16* Qb = Qr + ((size_t)bh * SEQ + qbase + f * 64 + wave * 16 + l15) * HD + quad * 8;
    aq[f][0] = *(const short8*)(Qb);
    aq[f][1] = *(const short8*)(Qb + 32);
    aq[f][2] = *(const short8*)(Qb + 64);   // quad>=2 reads past row end (mapped)
    if (quad >= 2) aq[f][2] = (short8)0;    // exact zero pad d>=80
  }

  f32x4 o[2][6];      // [frag][5 data d-tiles + 1 denominator tile]
#pragma unroll
  for (int f = 0; f < 2; f++)
    for (int nt = 0; nt < 6; nt++) o[f][nt] = (f32x4)0.f;
  float m_i[2] = {-3e38f, -3e38f};   // per-lane row-max state for qrow=l15

  const char* Kb8 = (const char*)(Kr + (size_t)bh * SEQ * HD);
  const char* Vb8 = (const char*)(Vt + (size_t)bh * HD * SEQ);
  const int nsteps = 2 * qblk + 2;
  const int rmax0 = qbase + wave * 16 + 15;   // frag0 last row (frag1 always active)

  for (int step = 0; step < nsteps; step++) {
    const int kvo = step * 64;
    const bool act0 = (kvo <= rmax0);

    __syncthreads();   // prior step's LDS reads done (also covers ones-init)
    {
      const char* kb = Kb8 + kvo * 160;
      const char* vb = Vb8 + kvo * 2;
#pragma unroll
      for (int it = 0; it < 6; it++) {
        const int j = tid + it * 256;
        if (j < 1424) {
          bf16* ldsb = stage + (it * 256 + wave * 64) * 8;   // wave-uniform
          gld16((j < 704) ? (kb + goff[it]) : (vb + goff[it]), ldsb);
        }
      }
    }
    __syncthreads();   // staging landed

    // S^T = K Q^T : C-layout kv=quad*4+r (per tile), qrow=l15
    f32x4 sv[2][4];
#pragma unroll
    for (int nt = 0; nt < 4; nt++) {
      const bf16* kr = &kt[(nt * 16 + l15) * 88 + quad * 8];
      short8 b0 = *(const short8*)(kr);
      short8 b1 = *(const short8*)(kr + 32);
      short8 b2 = *(const short8*)(kr + 64);  // k>=80 garbage killed by aq[..][2]=0
      if (act0) {
        f32x4 s = mfma16(b0, aq[0][0], (f32x4)0.f);
        s = mfma16(b1, aq[0][1], s);
        sv[0][nt] = mfma16(b2, aq[0][2], s);
      }
      f32x4 s1 = mfma16(b0, aq[1][0], (f32x4)0.f);
      s1 = mfma16(b1, aq[1][1], s1);
      sv[1][nt] = mfma16(b2, aq[1][2], s1);
    }

    // online softmax per frag; per lane: 16 values of qrow=l15
#pragma unroll
    for (int f = 0; f < 2; f++) {
      if (f == 0 && !act0) continue;
      const int mrel = qbase + f * 64 + wave * 16 - kvo;   // wave-uniform
      if (mrel < 63) {
        const int qrel = mrel + l15;
#pragma unroll
        for (int nt = 0; nt < 4; nt++) {
          f32x4 t = sv[f][nt];
#pragma unroll
          for (int r = 0; r < 4; r++)
            t[r] = (nt * 16 + quad * 4 + r <= qrel) ? t[r] : -3e38f;
          sv[f][nt] = t;
        }
      }
      float mx = fmaxf(fmaxf(sv[f][0][0], sv[f][0][1]), fmaxf(sv[f][0][2], sv[f][0][3]));
#pragma unroll
      for (int nt = 1; nt < 4; nt++)
        mx = fmaxf(mx, fmaxf(fmaxf(sv[f][nt][0], sv[f][nt][1]),
                             fmaxf(sv[f][nt][2], sv[f][nt][3])));
      mx = fmaxf(mx, __shfl_xor(mx, 16, 64));
      mx = fmaxf(mx, __shfl_xor(mx, 32, 64));
      const float mnew = fmaxf(m_i[f], mx);
      const float alpha = __expf(m_i[f] - mnew);
      m_i[f] = mnew;

      bf16* ptw = pt + (wave * 2 + f) * 1152;
#pragma unroll
      for (int nt = 0; nt < 4; nt++) {
        __align__(8) bf16 p4[4];
#pragma unroll
        for (int r = 0; r < 4; r++) p4[r] = f2bf(__expf(sv[f][nt][r] - mnew));
        *(unsigned long long*)&ptw[l15 * 72 + nt * 16 + quad * 4] =
            *(const unsigned long long*)p4;
      }
      // broadcast alpha to O's C-layout rows (quad*4+r) via lanes 0..15
      float av[4];
#pragma unroll
      for (int r = 0; r < 4; r++) av[r] = __shfl(alpha, quad * 4 + r, 64);
#pragma unroll
      for (int nt = 0; nt < 6; nt++) {
        f32x4 t = o[f][nt];
        t[0] *= av[0]; t[1] *= av[1]; t[2] *= av[2]; t[3] *= av[3];
        o[f][nt] = t;
      }
    }

    asm volatile("s_waitcnt lgkmcnt(0)" ::: "memory");   // P^T writes landed (per-wave)
    short8 pa00 = (short8)0, pa01 = (short8)0, pa10, pa11;
    {
      const bf16* p0 = pt + (wave * 2 + 0) * 1152 + l15 * 72 + quad * 8;
      const bf16* p1 = pt + (wave * 2 + 1) * 1152 + l15 * 72 + quad * 8;
      if (act0) { pa00 = *(const short8*)p0; pa01 = *(const short8*)(p0 + 32); }
      pa10 = *(const short8*)p1; pa11 = *(const short8*)(p1 + 32);
    }
    // O += P V : 6 d-tiles (tile 5 = denominator), vt reads shared by frags
#pragma unroll
    for (int nt = 0; nt < 6; nt++) {
      const bf16* vr = &vt[(nt * 16 + l15) * 72 + quad * 8];
      short8 v0 = *(const short8*)(vr);
      short8 v1 = *(const short8*)(vr + 32);
      if (act0) {
        o[0][nt] = mfma16(pa00, v0, o[0][nt]);
        o[0][nt] = mfma16(pa01, v1, o[0][nt]);
      }
      o[1][nt] = mfma16(pa10, v0, o[1][nt]);
      o[1][nt] = mfma16(pa11, v1, o[1][nt]);
    }
  }

  // epilogue: out[t][h*80+d] = O / l
  const int b = bh >> 5, h = bh & 31;
#pragma unroll
  for (int f = 0; f < 2; f++)
#pragma unroll
    for (int r = 0; r < 4; r++) {
      const float inv = 1.0f / o[f][5][r];
      const int trow = b * SEQ + qbase + f * 64 + wave * 16 + quad * 4 + r;
#pragma unroll
      for (int nt = 0; nt < 5; nt++)
        O[(size_t)trow * HID + h * HD + nt * 16 + l15] = f2bf(o[f][nt][r] * inv);
    }
}

// ---------------------------------------------------------------------------
extern "C" void kernel_launch(void* const* d_in, const int* in_sizes, int n_in,
                              void* d_out, int out_size, void* d_ws, size_t ws_size,
                              hipStream_t stream) {
  (void)in_sizes; (void)n_in; (void)ws_size;
  char* wsb = (char*)d_ws;

  int*  flag   = (int*) (wsb + 0);
  bf16* cos_c  = (bf16*)(wsb + 1024);
  bf16* sin_c  = (bf16*)(wsb + 165888);
  bf16* bqkv_c = (bf16*)(wsb + 329728);
  bf16* bo_c   = (bf16*)(wsb + 345088);
  bf16* wo_c   = (bf16*)(wsb + 1048576);         // -> 14,155,776
  bf16* qkv    = (bf16*)(wsb + 14155776);        // -> 77,070,336
  bf16* hid_c  = (bf16*)(wsb + 77070336);        // -> 98,041,856
  bf16* wqkv_c = (bf16*)(wsb + 98041856);        // -> 137,363,456
  bf16* Qr     = (bf16*)(wsb + 77070336);        // over hid_c (dead post-GEMM1)
  bf16* Kr     = (bf16*)(wsb + 98041856);        // over wqkv_c (dead post-GEMM1)
  bf16* Vt     = (bf16*)(wsb + 119013376);       // -> 139,984,896
  bf16* attn   = (bf16*)(wsb + 14155776);        // over qkv (dead)
  bf16* obuf   = (bf16*)(wsb + 35127296);        // over qkv+21M

  detect_kernel<<<1, 256, 0, stream>>>((const unsigned short*)d_in[0], flag);
  convert_kernel<<<1024, 256, 0, stream>>>(d_in[0], hid_c,  TTOT * HID / 8, flag);
  convert_kernel<<<1024, 256, 0, stream>>>(d_in[1], wqkv_c, QKVN * HID / 8, flag);
  convert_kernel<<<4,    256, 0, stream>>>(d_in[2], bqkv_c, QKVN / 8,       flag);
  convert_kernel<<<1024, 256, 0, stream>>>(d_in[3], wo_c,   HID * HID / 8,  flag);
  convert_kernel<<<2,    256, 0, stream>>>(d_in[4], bo_c,   HID / 8,        flag);
  convert_kernel<<<40,   256, 0, stream>>>(d_in[5], cos_c,  TTOT * 20 / 8,  flag);
  convert_kernel<<<40,   256, 0, stream>>>(d_in[6], sin_c,  TTOT * 20 / 8,  flag);

  gemm256_bias<<<dim3((TTOT / 256) * (QKVN / 256)), 512, 0, stream>>>(
      hid_c, wqkv_c, bqkv_c, qkv, TTOT, QKVN, HID);
  rope_kernel<<<dim3(TTOT), 256, 0, stream>>>(qkv, cos_c, sin_c, Qr, Kr);
  vtrans_kernel<<<dim3(64, SEQ / 64), 256, 0, stream>>>(qkv, Vt);
  attn_kernel<<<dim3(1024), 256, 0, stream>>>(Qr, Kr, Vt, attn);
  gemm256_bias<<<dim3((TTOT / 256) * (HID / 256)), 512, 0, stream>>>(
      attn, wo_c, bo_c, obuf, TTOT, HID, HID);
  emit_kernel<<<1024, 256, 0, stream>>>(obuf, d_out, out_size / 8, flag);
}

// Round 4
// 606.905 us; speedup vs baseline: 1.3275x; 1.3275x over previous
//
#include <hip/hip_runtime.h>
#include <hip/hip_bf16.h>

// Problem constants
#define HID   2560
#define NH    32
#define HD    80      // head dim
#define SEQ   2048
#define TTOT  4096    // B*S
#define QKVN  7680    // 3*HID

typedef float  f32x4  __attribute__((ext_vector_type(4)));
typedef short  short8 __attribute__((ext_vector_type(8)));
typedef __bf16 bf16x8 __attribute__((ext_vector_type(8)));
typedef __hip_bfloat16 bf16;

__device__ __forceinline__ float bf2f(bf16 h) { return __bfloat162float(h); }
__device__ __forceinline__ bf16  f2bf(float f) { return __float2bfloat16(f); }

__device__ __forceinline__ f32x4 mfma16(short8 a, short8 b, f32x4 c) {
  return __builtin_amdgcn_mfma_f32_16x16x32_bf16(
      __builtin_bit_cast(bf16x8, a), __builtin_bit_cast(bf16x8, b), c, 0, 0, 0);
}

// async global->LDS, 16B per lane: LDS dest = wave-uniform base + lane*16,
// global side is a per-lane gather.
typedef __attribute__((address_space(1))) const unsigned int as1_uint;
typedef __attribute__((address_space(3))) unsigned int       as3_uint;
__device__ __forceinline__ void gld16(const void* g, void* l) {
  __builtin_amdgcn_global_load_lds((as1_uint*)g, (as3_uint*)l, 16, 0, 0);
}

// ---------------------------------------------------------------------------
// Dtype detection (flag=1 -> inputs are f32; 0 -> bf16).
// ---------------------------------------------------------------------------
__global__ void detect_kernel(const unsigned short* __restrict__ hid, int* flag) {
  const int tid = threadIdx.x;  // 256
  const unsigned short u = hid[2 * (tid * 997)];
  const int e = (u >> 7) & 0xFF;
  const int sane = (u == 0 || (e >= 0x60 && e <= 0x8A)) ? 1 : 0;
  __shared__ int cnt;
  if (tid == 0) cnt = 0;
  __syncthreads();
  atomicAdd(&cnt, sane);
  __syncthreads();
  if (tid == 0) *flag = (cnt < 160) ? 1 : 0;
}

// Normalize float input to bf16, 8 elems/thread. n8 = n/8.
__global__ void convert_kernel(const void* __restrict__ src, bf16* __restrict__ dst,
                               int n8, const int* __restrict__ flag) {
  const bool isf32 = (*flag != 0);
  for (int i = blockIdx.x * 256 + threadIdx.x; i < n8; i += gridDim.x * 256) {
    if (isf32) {
      const float4* s = (const float4*)src;
      float4 a = s[2 * i], b = s[2 * i + 1];
      __align__(16) bf16 o8[8] = {f2bf(a.x), f2bf(a.y), f2bf(a.z), f2bf(a.w),
                                  f2bf(b.x), f2bf(b.y), f2bf(b.z), f2bf(b.w)};
      *(uint4*)(dst + 8 * i) = *(const uint4*)o8;
    } else {
      *(uint4*)(dst + 8 * i) = ((const uint4*)src)[i];
    }
  }
}

// Emit output in true dtype. n8 = n/8.
__global__ void emit_kernel(const bf16* __restrict__ src, void* __restrict__ dst,
                            int n8, const int* __restrict__ flag) {
  const bool isf32 = (*flag != 0);
  for (int i = blockIdx.x * 256 + threadIdx.x; i < n8; i += gridDim.x * 256) {
    uint4 v = *(const uint4*)(src + 8 * i);
    if (isf32) {
      const bf16* b = (const bf16*)&v;
      float4* d = (float4*)dst;
      d[2 * i]     = make_float4(bf2f(b[0]), bf2f(b[1]), bf2f(b[2]), bf2f(b[3]));
      d[2 * i + 1] = make_float4(bf2f(b[4]), bf2f(b[5]), bf2f(b[6]), bf2f(b[7]));
    } else {
      ((uint4*)dst)[i] = v;
    }
  }
}

// ---------------------------------------------------------------------------
// GEMM, 256x256 tile / BK=64 / 8 waves. 4-phase schedule with BALANCED
// per-phase LDS reads (8/4/8/4 b128 per wave) and a single cross-phase
// register set (b01 ping-pong). Round-1's 12/4/8/0 distribution made the
// read-heavy phase's LDS drain (~1150cy/CU) serialize ahead of its MFMA
// (620cy); round-3's deeper reg pipelining spilled (WRITE_SIZE 2x). This is
// the minimal rebalance: only b01 crosses a phase boundary (+16 VGPR).
//
//   ph1: read a03(8);  stage A[t+2]h0; bar; lgkm(0); MFMA a03 x b01cur ; bar
//   ph2: read b23(4);  stage A[t+2]h1; bar; lgkm(0); MFMA a03 x b23   ; bar
//   ph3: read a47(8);  stage B[t+2]h0; vmcnt(6); bar; lgkm(0);
//                                           MFMA a47 x b23            ; bar
//   ph4: read b01next(4) from lB[(t+1)&1]; stage B[t+2]h1;
//        MFMA a47 x b01cur (register-only, NO lgkm wait)              ; bar
//
// vmcnt(6) at ph3: FIFO-outstanding = [A+1(4), B+1(4), A+2(4), B+2h0(2)]=14
// -> drains A[t+1] (read next tile ph1) and B[t+1] (read THIS ph4); leaves 6.
// Never drains to 0 in steady state. A triple-buffered, B double-buffered
// (160 KiB LDS), depth-2 staging. Requires M%256==0, N%256==0, K%64==0.
//
// LDS swizzle: phys_byte = logical_byte ^ ((row&7)<<4) applied on the global
// source at stage time + on the ds_read address (both-sides involution).
// ---------------------------------------------------------------------------
__global__ __launch_bounds__(512, 2) void gemm256_bias(
    const bf16* __restrict__ A, const bf16* __restrict__ B,
    const bf16* __restrict__ bias, bf16* __restrict__ C,
    int M, int N, int K)
{
  __shared__ __align__(16) bf16 lA[3][16384];   // 3 x 256rows x 64cols
  __shared__ __align__(16) bf16 lB[2][16384];   // 2 x 256rows x 64cols

  const int tid  = threadIdx.x;
  const int wid  = tid >> 6;
  const int lane = tid & 63;
  const int quad = lane >> 4;
  const int l15  = lane & 15;
  const int wr   = wid >> 2;   // 0..1 -> 128 rows each
  const int wc   = wid & 3;    // 0..3 -> 64 cols each

  // bijective XCD-aware block swizzle (m204)
  int wgid;
  {
    const int nwg = gridDim.x;
    const int q = nwg >> 3, r = nwg & 7;
    const int xcd = blockIdx.x & 7, lin = blockIdx.x >> 3;
    wgid = (xcd < r ? xcd * (q + 1) : r * (q + 1) + (xcd - r) * q) + lin;
  }
  const int gx = M >> 8;
  const int m0 = (wgid % gx) << 8;
  const int n0 = (wgid / gx) << 8;

  const int NT = K >> 6;   // K-tiles of 64

  // Staging geometry: half-tile = 128 rows x 64 cols = 1024 chunks of 16B.
  // Thread handles phys chunks tid and tid+512 (same swizzled col, +64 rows).
  const int rr   = tid >> 3;                               // phys row 0..63
  const int cbyt = ((tid & 7) << 4) ^ ((rr & 7) << 4);     // logical col byte
  const size_t o1 = (size_t)rr * K + (cbyt >> 1);
  const size_t o2 = o1 + (size_t)64 * K;

  const bf16* Ab = A + (size_t)m0 * K;
  const bf16* Bb = B + (size_t)n0 * K;

#define STAGEA(bufsel, half, tt)                                               \
  {                                                                            \
    const bf16* _s = Ab + (size_t)(half) * 128 * K + (size_t)(tt) * 64;        \
    bf16* _d = &lA[bufsel][(half) * 8192 + wid * 512];                         \
    gld16(_s + o1, _d);                                                        \
    gld16(_s + o2, _d + 4096);                                                 \
  }
#define STAGEB(bufsel, half, tt)                                               \
  {                                                                            \
    const bf16* _s = Bb + (size_t)(half) * 128 * K + (size_t)(tt) * 64;        \
    bf16* _d = &lB[bufsel][(half) * 8192 + wid * 512];                         \
    gld16(_s + o1, _d);                                                        \
    gld16(_s + o2, _d + 4096);                                                 \
  }

#define WAIT_LGKM0                                                             \
  do {                                                                         \
    asm volatile("s_waitcnt lgkmcnt(0)" ::: "memory");                         \
    __builtin_amdgcn_sched_barrier(0);                                         \
  } while (0)
#define WAIT_VM(n) asm volatile("s_waitcnt vmcnt(" #n ")" ::: "memory")

  // frag-read swizzled 16B-column offsets (bytes) for ks=0,1
  const int csw0 = ((quad ^ (l15 & 7)) << 4);
  const int csw1 = (((4 | quad) ^ (l15 & 7)) << 4);

  f32x4 acc[8][4];
#pragma unroll
  for (int i = 0; i < 8; ++i)
#pragma unroll
    for (int j = 0; j < 4; ++j) acc[i][j] = (f32x4)0.f;

  short8 a[4][2], b23[2][2], b01A[2][2], b01B[2][2];

  // Prologue: stage tiles 0,1 in full; wait tile0; pre-read b01 of tile0.
  STAGEA(0, 0, 0); STAGEA(0, 1, 0);
  STAGEB(0, 0, 0); STAGEB(0, 1, 0);
  if (NT > 1) {
    STAGEA(1, 0, 1); STAGEA(1, 1, 1);
    STAGEB(1, 0, 1); STAGEB(1, 1, 1);
    WAIT_VM(8);                        // tile0's 8 loads landed
  } else {
    WAIT_VM(0);
  }
  __builtin_amdgcn_s_barrier();
#pragma unroll
  for (int n = 0; n < 2; ++n) {
    const char* p = (const char*)lB[0] + (size_t)(wc * 64 + n * 16 + l15) * 128;
    b01A[n][0] = *(const short8*)(p + csw0);
    b01A[n][1] = *(const short8*)(p + csw1);
  }
  // steady-state invariant entering each tile: b01cur's 4 ds_reads in flight.

#define KTILE(T, B01U, B01L)                                                   \
  do {                                                                         \
    const int _t = (T);                                                        \
    const bf16* Al = lA[_t % 3];                                               \
    const bf16* Bl = lB[_t & 1];                                               \
    const bf16* Bln = lB[(_t + 1) & 1];                                        \
    const bool stg = (_t + 2 < NT);                                            \
    const bool nxt = (_t + 1 < NT);                                            \
    /* ---- ph1: read a03; stage A[t+2]h0; MFMA a03 x b01cur */                \
    _Pragma("unroll") for (int mi = 0; mi < 4; ++mi) {                         \
      const char* p = (const char*)Al + (size_t)(wr * 128 + mi * 16 + l15) * 128; \
      a[mi][0] = *(const short8*)(p + csw0);                                   \
      a[mi][1] = *(const short8*)(p + csw1);                                   \
    }                                                                          \
    if (stg) STAGEA((_t + 2) % 3, 0, _t + 2);                                  \
    __builtin_amdgcn_s_barrier();                                              \
    WAIT_LGKM0;                                                                \
    __builtin_amdgcn_s_setprio(1);                                             \
    _Pragma("unroll") for (int mi = 0; mi < 4; ++mi)                           \
      _Pragma("unroll") for (int n = 0; n < 2; ++n) {                          \
        acc[mi][n] = mfma16(a[mi][0], B01U[n][0], acc[mi][n]);                 \
        acc[mi][n] = mfma16(a[mi][1], B01U[n][1], acc[mi][n]);                 \
      }                                                                        \
    __builtin_amdgcn_s_setprio(0);                                             \
    __builtin_amdgcn_s_barrier();                                              \
    /* ---- ph2: read b23; stage A[t+2]h1; MFMA a03 x b23 */                   \
    _Pragma("unroll") for (int n = 0; n < 2; ++n) {                            \
      const char* p = (const char*)Bl + (size_t)(wc * 64 + (2 + n) * 16 + l15) * 128; \
      b23[n][0] = *(const short8*)(p + csw0);                                  \
      b23[n][1] = *(const short8*)(p + csw1);                                  \
    }                                                                          \
    if (stg) STAGEA((_t + 2) % 3, 1, _t + 2);                                  \
    __builtin_amdgcn_s_barrier();                                              \
    WAIT_LGKM0;                                                                \
    __builtin_amdgcn_s_setprio(1);                                             \
    _Pragma("unroll") for (int mi = 0; mi < 4; ++mi)                           \
      _Pragma("unroll") for (int n = 0; n < 2; ++n) {                          \
        acc[mi][2 + n] = mfma16(a[mi][0], b23[n][0], acc[mi][2 + n]);          \
        acc[mi][2 + n] = mfma16(a[mi][1], b23[n][1], acc[mi][2 + n]);          \
      }                                                                        \
    __builtin_amdgcn_s_setprio(0);                                             \
    __builtin_amdgcn_s_barrier();                                              \
    /* ---- ph3: read a47 (reuse a[]); stage B[t+2]h0; vmcnt(6); MFMA a47xb23 */ \
    _Pragma("unroll") for (int mi = 0; mi < 4; ++mi) {                         \
      const char* p = (const char*)Al + (size_t)(wr * 128 + 64 + mi * 16 + l15) * 128; \
      a[mi][0] = *(const short8*)(p + csw0);                                   \
      a[mi][1] = *(const short8*)(p + csw1);                                   \
    }                                                                          \
    if (stg) STAGEB(_t & 1, 0, _t + 2);                                        \
    if (stg) { WAIT_VM(6); } else { WAIT_VM(0); }                              \
    __builtin_amdgcn_s_barrier();                                              \
    WAIT_LGKM0;                                                                \
    __builtin_amdgcn_s_setprio(1);                                             \
    _Pragma("unroll") for (int mi = 0; mi < 4; ++mi)                           \
      _Pragma("unroll") for (int n = 0; n < 2; ++n) {                          \
        acc[4 + mi][2 + n] = mfma16(a[mi][0], b23[n][0], acc[4 + mi][2 + n]);  \
        acc[4 + mi][2 + n] = mfma16(a[mi][1], b23[n][1], acc[4 + mi][2 + n]);  \
      }                                                                        \
    __builtin_amdgcn_s_setprio(0);                                             \
    __builtin_amdgcn_s_barrier();                                              \
    /* ---- ph4: read b01next (B[t+1] landed via ph3 vmcnt); stage B[t+2]h1;   \
            MFMA a47 x b01cur -- register-only, no lgkm wait */                \
    if (nxt) {                                                                 \
      _Pragma("unroll") for (int n = 0; n < 2; ++n) {                          \
        const char* p = (const char*)Bln + (size_t)(wc * 64 + n * 16 + l15) * 128; \
        B01L[n][0] = *(const short8*)(p + csw0);                               \
        B01L[n][1] = *(const short8*)(p + csw1);                               \
      }                                                                        \
    }                                                                          \
    if (stg) STAGEB(_t & 1, 1, _t + 2);                                        \
    __builtin_amdgcn_s_setprio(1);                                             \
    _Pragma("unroll") for (int mi = 0; mi < 4; ++mi)                           \
      _Pragma("unroll") for (int n = 0; n < 2; ++n) {                          \
        acc[4 + mi][n] = mfma16(a[mi][0], B01U[n][0], acc[4 + mi][n]);         \
        acc[4 + mi][n] = mfma16(a[mi][1], B01U[n][1], acc[4 + mi][n]);         \
      }                                                                        \
    __builtin_amdgcn_s_setprio(0);                                             \
    __builtin_amdgcn_s_barrier();                                              \
  } while (0)

  for (int t = 0; t < NT; t += 2) {
    KTILE(t, b01A, b01B);
    if (t + 1 < NT) KTILE(t + 1, b01B, b01A);
  }
#undef KTILE
#undef STAGEA
#undef STAGEB
#undef WAIT_LGKM0
#undef WAIT_VM

  // Epilogue: C += bias
  const int crow = m0 + wr * 128 + quad * 4;
  const int ccol = n0 + wc * 64 + l15;
#pragma unroll
  for (int n = 0; n < 4; ++n) {
    const float bv = bf2f(bias[ccol + n * 16]);
#pragma unroll
    for (int mi = 0; mi < 8; ++mi) {
      const int rb = crow + mi * 16;
#pragma unroll
      for (int r = 0; r < 4; ++r)
        C[(size_t)(rb + r) * N + ccol + n * 16] = f2bf(acc[mi][n][r] + bv);
    }
  }
}

// ---------------------------------------------------------------------------
// RoPE + repack: qkv[t][7680] -> Qr/Kr [bh][s][80]; Q pre-scaled by 1/sqrt(80)
// ---------------------------------------------------------------------------
__global__ __launch_bounds__(256) void rope_kernel(
    const bf16* __restrict__ qkv, const bf16* __restrict__ cosb,
    const bf16* __restrict__ sinb, bf16* __restrict__ Qr, bf16* __restrict__ Kr)
{
  const int t = blockIdx.x;
  const int b = t >> 11;
  const int s = t & 2047;
  const float qscale = 0.11180339887498949f;

  __shared__ float cs[20], sn[20];
  if (threadIdx.x < 20) cs[threadIdx.x] = bf2f(cosb[t * 20 + threadIdx.x]);
  if (threadIdx.x >= 32 && threadIdx.x < 52)
    sn[threadIdx.x - 32] = bf2f(sinb[t * 20 + (threadIdx.x - 32)]);
  __syncthreads();

  const bf16* qrow = qkv + (size_t)t * QKVN;
  const bf16* krow = qrow + HID;

  for (int idx = threadIdx.x; idx < HID; idx += 256) {
    const int h = idx / HD, d = idx % HD;
    const size_t off = ((size_t)(b * NH + h) * SEQ + s) * HD + d;
    float q, k;
    if (d < 20) {
      q = bf2f(qrow[h * HD + d]) * cs[d] - bf2f(qrow[h * HD + d + 20]) * sn[d];
      k = bf2f(krow[h * HD + d]) * cs[d] - bf2f(krow[h * HD + d + 20]) * sn[d];
    } else if (d < 40) {
      q = bf2f(qrow[h * HD + d - 20]) * sn[d - 20] + bf2f(qrow[h * HD + d]) * cs[d - 20];
      k = bf2f(krow[h * HD + d - 20]) * sn[d - 20] + bf2f(krow[h * HD + d]) * cs[d - 20];
    } else {
      q = bf2f(qrow[h * HD + d]);
      k = bf2f(krow[h * HD + d]);
    }
    Qr[off] = f2bf(q * qscale);
    Kr[off] = f2bf(k);
  }
}

// ---------------------------------------------------------------------------
// V transpose: qkv V-part [t][h*80+d] -> Vt [bh][d][s]
// ---------------------------------------------------------------------------
__global__ __launch_bounds__(256) void vtrans_kernel(
    const bf16* __restrict__ qkv, bf16* __restrict__ Vt)
{
  const int bh = blockIdx.x;
  const int s0 = blockIdx.y * 64;
  const int b = bh >> 5, h = bh & 31;
  __shared__ bf16 tile[64][81];

  for (int e = threadIdx.x; e < 64 * HD; e += 256) {
    const int r = e / HD, d = e % HD;
    tile[r][d] = qkv[(size_t)(b * SEQ + s0 + r) * QKVN + 2 * HID + h * HD + d];
  }
  __syncthreads();
  for (int e = threadIdx.x; e < 64 * HD; e += 256) {
    const int d = e >> 6, r = e & 63;
    Vt[((size_t)bh * HD + d) * SEQ + s0 + r] = tile[r][d];
  }
}

// ---------------------------------------------------------------------------
// Flash attention v4, causal. Block = 128 q-rows (4 waves x 2 frags of 16),
// kv-step 64. Staging via global_load_lds (1424 contiguous 16B chunks: K tile
// [64][88] + V tile rows 0..79 of [96][72]); V rows 80..95 = ones (denominator
// accumulated as PV's 6th d-tile). QK^T computed TRANSPOSED (K as A-operand,
// Q as B-operand -> S^T C-layout: kv=quad*4+r, qrow=l15) so softmax rows are
// per-lane and P^T is written with packed b64 stores straight into A-layout.
// ---------------------------------------------------------------------------
__global__ __launch_bounds__(256, 3) void attn_kernel(
    const bf16* __restrict__ Qr, const bf16* __restrict__ Kr,
    const bf16* __restrict__ Vt, bf16* __restrict__ O)
{
  // XCD-aware decode: 16 q-blocks of a bh share an XCD; heavy qblk first
  const int raw  = blockIdx.x;          // 0..1023
  const int slot = raw >> 3;
  const int qblk = 15 - (slot & 15);
  const int bh   = ((slot >> 4) << 3) + (raw & 7);

  const int tid  = threadIdx.x;
  const int wave = tid >> 6;
  const int lane = tid & 63;
  const int quad = lane >> 4;
  const int l15  = lane & 15;
  const int qbase = qblk * 128;

  // staging region: 1424 chunks *16B = kt[64][88] then vt rows 0..79 of [96][72]
  // (kt col-pad 80..87 and vt col-pad 64..71 are garbage chunks, never read
  //  or killed by zero operands); vt rows 80..95 = ones, init'd once.
  __shared__ __align__(16) bf16 stage[12544];
  __shared__ __align__(16) bf16 pt[4 * 2 * 1152];   // per wave x frag: [16][72] P^T

  bf16* kt = stage;            // 64*88
  bf16* vt = stage + 5632;     // 96*72

  if (tid < 144) {
    const unsigned one2 = 0x3F803F80u;  // two bf16 1.0
    *(uint4*)&vt[5760 + tid * 8] = (uint4){one2, one2, one2, one2};
  }

  // staging chunk -> static global byte offset (c==pad chunk -> row start)
  int goff[6];
#pragma unroll
  for (int it = 0; it < 6; it++) {
    const int j = tid + it * 256;
    if (j < 704) {                       // K: row r (160B) as 10 chunks + 1 pad
      const int r = j / 11; int c = j - 11 * r; if (c > 9) c = 0;
      goff[it] = r * 160 + c * 16;
    } else {                             // V: row r (128B) as 8 chunks + 1 pad
      const int j2 = j - 704;
      const int r = j2 / 9; int c = j2 - 9 * r; if (c > 7) c = 0;
      goff[it] = r * 4096 + c * 16;
    }
  }

  // Q fragments: 2 frags x 3 K-chunks, resident (scale pre-folded at RoPE)
  short8 aq[2][3];
#pragma unroll
  for (int f = 0; f < 2; f++) {
    const bf16* Qb = Qr + ((size_t)bh * SEQ + qbase + f * 64 + wave * 16 + l15) * HD + quad * 8;
    aq[f][0] = *(const short8*)(Qb);
    aq[f][1] = *(const short8*)(Qb + 32);
    aq[f][2] = *(const short8*)(Qb + 64);   // quad>=2 reads past row end (mapped)
    if (quad >= 2) aq[f][2] = (short8)0;    // exact zero pad d>=80
  }

  f32x4 o[2][6];      // [frag][5 data d-tiles + 1 denominator tile]
#pragma unroll
  for (int f = 0; f < 2; f++)
    for (int nt = 0; nt < 6; nt++) o[f][nt] = (f32x4)0.f;
  float m_i[2] = {-3e38f, -3e38f};   // per-lane row-max state for qrow=l15

  const char* Kb8 = (const char*)(Kr + (size_t)bh * SEQ * HD);
  const char* Vb8 = (const char*)(Vt + (size_t)bh * HD * SEQ);
  const int nsteps = 2 * qblk + 2;
  const int rmax0 = qbase + wave * 16 + 15;   // frag0 last row (frag1 always active)

  for (int step = 0; step < nsteps; step++) {
    const int kvo = step * 64;
    const bool act0 = (kvo <= rmax0);

    __syncthreads();   // prior step's LDS reads done (also covers ones-init)
    {
      const char* kb = Kb8 + kvo * 160;
      const char* vb = Vb8 + kvo * 2;
#pragma unroll
      for (int it = 0; it < 6; it++) {
        const int j = tid + it * 256;
        if (j < 1424) {
          bf16* ldsb = stage + (it * 256 + wave * 64) * 8;   // wave-uniform
          gld16((j < 704) ? (kb + goff[it]) : (vb + goff[it]), ldsb);
        }
      }
    }
    __syncthreads();   // staging landed

    // S^T = K Q^T : C-layout kv=quad*4+r (per tile), qrow=l15
    f32x4 sv[2][4];
#pragma unroll
    for (int nt = 0; nt < 4; nt++) {
      const bf16* kr = &kt[(nt * 16 + l15) * 88 + quad * 8];
      short8 b0 = *(const short8*)(kr);
      short8 b1 = *(const short8*)(kr + 32);
      short8 b2 = *(const short8*)(kr + 64);  // k>=80 garbage killed by aq[..][2]=0
      if (act0) {
        f32x4 s = mfma16(b0, aq[0][0], (f32x4)0.f);
        s = mfma16(b1, aq[0][1], s);
        sv[0][nt] = mfma16(b2, aq[0][2], s);
      }
      f32x4 s1 = mfma16(b0, aq[1][0], (f32x4)0.f);
      s1 = mfma16(b1, aq[1][1], s1);
      sv[1][nt] = mfma16(b2, aq[1][2], s1);
    }

    // online softmax per frag; per lane: 16 values of qrow=l15
#pragma unroll
    for (int f = 0; f < 2; f++) {
      if (f == 0 && !act0) continue;
      const int mrel = qbase + f * 64 + wave * 16 - kvo;   // wave-uniform
      if (mrel < 63) {
        const int qrel = mrel + l15;
#pragma unroll
        for (int nt = 0; nt < 4; nt++) {
          f32x4 t = sv[f][nt];
#pragma unroll
          for (int r = 0; r < 4; r++)
            t[r] = (nt * 16 + quad * 4 + r <= qrel) ? t[r] : -3e38f;
          sv[f][nt] = t;
        }
      }
      float mx = fmaxf(fmaxf(sv[f][0][0], sv[f][0][1]), fmaxf(sv[f][0][2], sv[f][0][3]));
#pragma unroll
      for (int nt = 1; nt < 4; nt++)
        mx = fmaxf(mx, fmaxf(fmaxf(sv[f][nt][0], sv[f][nt][1]),
                             fmaxf(sv[f][nt][2], sv[f][nt][3])));
      mx = fmaxf(mx, __shfl_xor(mx, 16, 64));
      mx = fmaxf(mx, __shfl_xor(mx, 32, 64));
      const float mnew = fmaxf(m_i[f], mx);
      const float alpha = __expf(m_i[f] - mnew);
      m_i[f] = mnew;

      bf16* ptw = pt + (wave * 2 + f) * 1152;
#pragma unroll
      for (int nt = 0; nt < 4; nt++) {
        __align__(8) bf16 p4[4];
#pragma unroll
        for (int r = 0; r < 4; r++) p4[r] = f2bf(__expf(sv[f][nt][r] - mnew));
        *(unsigned long long*)&ptw[l15 * 72 + nt * 16 + quad * 4] =
            *(const unsigned long long*)p4;
      }
      // broadcast alpha to O's C-layout rows (quad*4+r) via lanes 0..15
      float av[4];
#pragma unroll
      for (int r = 0; r < 4; r++) av[r] = __shfl(alpha, quad * 4 + r, 64);
#pragma unroll
      for (int nt = 0; nt < 6; nt++) {
        f32x4 t = o[f][nt];
        t[0] *= av[0]; t[1] *= av[1]; t[2] *= av[2]; t[3] *= av[3];
        o[f][nt] = t;
      }
    }

    asm volatile("s_waitcnt lgkmcnt(0)" ::: "memory");   // P^T writes landed (per-wave)
    short8 pa00 = (short8)0, pa01 = (short8)0, pa10, pa11;
    {
      const bf16* p0 = pt + (wave * 2 + 0) * 1152 + l15 * 72 + quad * 8;
      const bf16* p1 = pt + (wave * 2 + 1) * 1152 + l15 * 72 + quad * 8;
      if (act0) { pa00 = *(const short8*)p0; pa01 = *(const short8*)(p0 + 32); }
      pa10 = *(const short8*)p1; pa11 = *(const short8*)(p1 + 32);
    }
    // O += P V : 6 d-tiles (tile 5 = denominator), vt reads shared by frags
#pragma unroll
    for (int nt = 0; nt < 6; nt++) {
      const bf16* vr = &vt[(nt * 16 + l15) * 72 + quad * 8];
      short8 v0 = *(const short8*)(vr);
      short8 v1 = *(const short8*)(vr + 32);
      if (act0) {
        o[0][nt] = mfma16(pa00, v0, o[0][nt]);
        o[0][nt] = mfma16(pa01, v1, o[0][nt]);
      }
      o[1][nt] = mfma16(pa10, v0, o[1][nt]);
      o[1][nt] = mfma16(pa11, v1, o[1][nt]);
    }
  }

  // epilogue: out[t][h*80+d] = O / l
  const int b = bh >> 5, h = bh & 31;
#pragma unroll
  for (int f = 0; f < 2; f++)
#pragma unroll
    for (int r = 0; r < 4; r++) {
      const float inv = 1.0f / o[f][5][r];
      const int trow = b * SEQ + qbase + f * 64 + wave * 16 + quad * 4 + r;
#pragma unroll
      for (int nt = 0; nt < 5; nt++)
        O[(size_t)trow * HID + h * HD + nt * 16 + l15] = f2bf(o[f][nt][r] * inv);
    }
}

// ---------------------------------------------------------------------------
extern "C" void kernel_launch(void* const* d_in, const int* in_sizes, int n_in,
                              void* d_out, int out_size, void* d_ws, size_t ws_size,
                              hipStream_t stream) {
  (void)in_sizes; (void)n_in; (void)ws_size;
  char* wsb = (char*)d_ws;

  int*  flag   = (int*) (wsb + 0);
  bf16* cos_c  = (bf16*)(wsb + 1024);
  bf16* sin_c  = (bf16*)(wsb + 165888);
  bf16* bqkv_c = (bf16*)(wsb + 329728);
  bf16* bo_c   = (bf16*)(wsb + 345088);
  bf16* wo_c   = (bf16*)(wsb + 1048576);         // -> 14,155,776
  bf16* qkv    = (bf16*)(wsb + 14155776);        // -> 77,070,336
  bf16* hid_c  = (bf16*)(wsb + 77070336);        // -> 98,041,856
  bf16* wqkv_c = (bf16*)(wsb + 98041856);        // -> 137,363,456
  bf16* Qr     = (bf16*)(wsb + 77070336);        // over hid_c (dead post-GEMM1)
  bf16* Kr     = (bf16*)(wsb + 98041856);        // over wqkv_c (dead post-GEMM1)
  bf16* Vt     = (bf16*)(wsb + 119013376);       // -> 139,984,896
  bf16* attn   = (bf16*)(wsb + 14155776);        // over qkv (dead)
  bf16* obuf   = (bf16*)(wsb + 35127296);        // over qkv+21M

  detect_kernel<<<1, 256, 0, stream>>>((const unsigned short*)d_in[0], flag);
  convert_kernel<<<1024, 256, 0, stream>>>(d_in[0], hid_c,  TTOT * HID / 8, flag);
  convert_kernel<<<1024, 256, 0, stream>>>(d_in[1], wqkv_c, QKVN * HID / 8, flag);
  convert_kernel<<<4,    256, 0, stream>>>(d_in[2], bqkv_c, QKVN / 8,       flag);
  convert_kernel<<<1024, 256, 0, stream>>>(d_in[3], wo_c,   HID * HID / 8,  flag);
  convert_kernel<<<2,    256, 0, stream>>>(d_in[4], bo_c,   HID / 8,        flag);
  convert_kernel<<<40,   256, 0, stream>>>(d_in[5], cos_c,  TTOT * 20 / 8,  flag);
  convert_kernel<<<40,   256, 0, stream>>>(d_in[6], sin_c,  TTOT * 20 / 8,  flag);

  gemm256_bias<<<dim3((TTOT / 256) * (QKVN / 256)), 512, 0, stream>>>(
      hid_c, wqkv_c, bqkv_c, qkv, TTOT, QKVN, HID);
  rope_kernel<<<dim3(TTOT), 256, 0, stream>>>(qkv, cos_c, sin_c, Qr, Kr);
  vtrans_kernel<<<dim3(64, SEQ / 64), 256, 0, stream>>>(qkv, Vt);
  attn_kernel<<<dim3(1024), 256, 0, stream>>>(Qr, Kr, Vt, attn);
  gemm256_bias<<<dim3((TTOT / 256) * (HID / 256)), 512, 0, stream>>>(
      attn, wo_c, bo_c, obuf, TTOT, HID, HID);
  emit_kernel<<<1024, 256, 0, stream>>>(obuf, d_out, out_size / 8, flag);
}

// Round 5
// 591.663 us; speedup vs baseline: 1.3617x; 1.0258x over previous
//
#include <hip/hip_runtime.h>
#include <hip/hip_bf16.h>

// Problem constants
#define HID   2560
#define NH    32
#define HD    80      // head dim
#define SEQ   2048
#define TTOT  4096    // B*S
#define QKVN  7680    // 3*HID

typedef float  f32x4  __attribute__((ext_vector_type(4)));
typedef short  short8 __attribute__((ext_vector_type(8)));
typedef __bf16 bf16x8 __attribute__((ext_vector_type(8)));
typedef __hip_bfloat16 bf16;

__device__ __forceinline__ float bf2f(bf16 h) { return __bfloat162float(h); }
__device__ __forceinline__ bf16  f2bf(float f) { return __float2bfloat16(f); }

__device__ __forceinline__ f32x4 mfma16(short8 a, short8 b, f32x4 c) {
  return __builtin_amdgcn_mfma_f32_16x16x32_bf16(
      __builtin_bit_cast(bf16x8, a), __builtin_bit_cast(bf16x8, b), c, 0, 0, 0);
}

// async global->LDS, 16B per lane: LDS dest = wave-uniform base + lane*16,
// global side is a per-lane gather.
typedef __attribute__((address_space(1))) const unsigned int as1_uint;
typedef __attribute__((address_space(3))) unsigned int       as3_uint;
__device__ __forceinline__ void gld16(const void* g, void* l) {
  __builtin_amdgcn_global_load_lds((as1_uint*)g, (as3_uint*)l, 16, 0, 0);
}

// ---------------------------------------------------------------------------
// Dtype detection (flag=1 -> inputs are f32; 0 -> bf16).
// ---------------------------------------------------------------------------
__global__ void detect_kernel(const unsigned short* __restrict__ hid, int* flag) {
  const int tid = threadIdx.x;  // 256
  const unsigned short u = hid[2 * (tid * 997)];
  const int e = (u >> 7) & 0xFF;
  const int sane = (u == 0 || (e >= 0x60 && e <= 0x8A)) ? 1 : 0;
  __shared__ int cnt;
  if (tid == 0) cnt = 0;
  __syncthreads();
  atomicAdd(&cnt, sane);
  __syncthreads();
  if (tid == 0) *flag = (cnt < 160) ? 1 : 0;
}

// Normalize float input to bf16, 8 elems/thread. n8 = n/8.
__global__ void convert_kernel(const void* __restrict__ src, bf16* __restrict__ dst,
                               int n8, const int* __restrict__ flag) {
  const bool isf32 = (*flag != 0);
  for (int i = blockIdx.x * 256 + threadIdx.x; i < n8; i += gridDim.x * 256) {
    if (isf32) {
      const float4* s = (const float4*)src;
      float4 a = s[2 * i], b = s[2 * i + 1];
      __align__(16) bf16 o8[8] = {f2bf(a.x), f2bf(a.y), f2bf(a.z), f2bf(a.w),
                                  f2bf(b.x), f2bf(b.y), f2bf(b.z), f2bf(b.w)};
      *(uint4*)(dst + 8 * i) = *(const uint4*)o8;
    } else {
      *(uint4*)(dst + 8 * i) = ((const uint4*)src)[i];
    }
  }
}

// Emit output in true dtype. n8 = n/8.
__global__ void emit_kernel(const bf16* __restrict__ src, void* __restrict__ dst,
                            int n8, const int* __restrict__ flag) {
  const bool isf32 = (*flag != 0);
  for (int i = blockIdx.x * 256 + threadIdx.x; i < n8; i += gridDim.x * 256) {
    uint4 v = *(const uint4*)(src + 8 * i);
    if (isf32) {
      const bf16* b = (const bf16*)&v;
      float4* d = (float4*)dst;
      d[2 * i]     = make_float4(bf2f(b[0]), bf2f(b[1]), bf2f(b[2]), bf2f(b[3]));
      d[2 * i + 1] = make_float4(bf2f(b[4]), bf2f(b[5]), bf2f(b[6]), bf2f(b[7]));
    } else {
      ((uint4*)dst)[i] = v;
    }
  }
}

// ---------------------------------------------------------------------------
// GEMM, 256x256 tile / BK=64 / 8 waves. 4-cluster schedule with ONLY TWO
// BARRIERS PER K-TILE (was 8). R1/R2/R4 all plateaued at MfmaUtil 37% with
// identical LDS traffic: the per-phase {barrier; lgkm(0); MFMA; barrier}
// lockstep made all 8 waves drain LDS (~600cy) then MFMA (~620cy) in strict
// alternation. Removing the MFMA-bracketing barriers lets the 2 waves/SIMD
// antiphase naturally (LDS port serializes their drains; matrix pipe
// serializes their MFMA), overlapping drain under MFMA. Register pressure
// unchanged vs R4 (arch-VGPR budget is 128: acc=128 AGPR at 2 waves/SIMD).
//
//   ph1: read a03(8); stage A[t+2]h0; lgkm(0); MFMA a03 x b01cur
//   ph2: read b23(4); stage A[t+2]h1; lgkm(0); MFMA a03 x b23
//   ph3: read a47(8); stage B[t+2]h0; vmcnt(6); BARRIER; lgkm(0); MFMA a47xb23
//   ph4: read b01next(4) from lB[(t+1)&1]; stage B[t+2]h1;
//        MFMA a47 x b01cur (register-only); BARRIER
//
// Hazards at 2 barriers/tile (verified):
//  - staging visibility: A[t],B[t] vmcnt-drained at t-1's ph3 vmcnt(6) and
//    published by t-1's ph3 barrier; B[t+1] (read by ph4 prefetch) drained by
//    THIS tile's vmcnt(6)+barrier.
//  - WAR stage-A[t+2] (ph1) vs t-1's reads of lA[(t-1)%3]: all such reads
//    drain before t-1's tile-end barrier; stage issues after it.
//  - WAR stage-B[t+2] (ph3/ph4) vs reads of lB[t&1] (b01cur drained ph1,
//    b23 drained ph2): both precede the ph3 barrier; stages follow it.
// vmcnt(6) at ph3: outstanding FIFO = [A+1(4),B+1(4),A+2(4),B+2h0(2)]=14 ->
// drains A[t+1],B[t+1], leaves 6 in flight across the barrier.
// A triple-buffered, B double-buffered (160 KiB LDS), depth-2 staging.
// Requires M%256==0, N%256==0, K%64==0.
//
// LDS swizzle: phys_byte = logical_byte ^ ((row&7)<<4) applied on the global
// source at stage time + on the ds_read address (both-sides involution).
// ---------------------------------------------------------------------------
__global__ __launch_bounds__(512, 2) void gemm256_bias(
    const bf16* __restrict__ A, const bf16* __restrict__ B,
    const bf16* __restrict__ bias, bf16* __restrict__ C,
    int M, int N, int K)
{
  __shared__ __align__(16) bf16 lA[3][16384];   // 3 x 256rows x 64cols
  __shared__ __align__(16) bf16 lB[2][16384];   // 2 x 256rows x 64cols

  const int tid  = threadIdx.x;
  const int wid  = tid >> 6;
  const int lane = tid & 63;
  const int quad = lane >> 4;
  const int l15  = lane & 15;
  const int wr   = wid >> 2;   // 0..1 -> 128 rows each
  const int wc   = wid & 3;    // 0..3 -> 64 cols each

  // bijective XCD-aware block swizzle (m204)
  int wgid;
  {
    const int nwg = gridDim.x;
    const int q = nwg >> 3, r = nwg & 7;
    const int xcd = blockIdx.x & 7, lin = blockIdx.x >> 3;
    wgid = (xcd < r ? xcd * (q + 1) : r * (q + 1) + (xcd - r) * q) + lin;
  }
  const int gx = M >> 8;
  const int m0 = (wgid % gx) << 8;
  const int n0 = (wgid / gx) << 8;

  const int NT = K >> 6;   // K-tiles of 64

  // Staging geometry: half-tile = 128 rows x 64 cols = 1024 chunks of 16B.
  // Thread handles phys chunks tid and tid+512 (same swizzled col, +64 rows).
  const int rr   = tid >> 3;                               // phys row 0..63
  const int cbyt = ((tid & 7) << 4) ^ ((rr & 7) << 4);     // logical col byte
  const size_t o1 = (size_t)rr * K + (cbyt >> 1);
  const size_t o2 = o1 + (size_t)64 * K;

  const bf16* Ab = A + (size_t)m0 * K;
  const bf16* Bb = B + (size_t)n0 * K;

#define STAGEA(bufsel, half, tt)                                               \
  {                                                                            \
    const bf16* _s = Ab + (size_t)(half) * 128 * K + (size_t)(tt) * 64;        \
    bf16* _d = &lA[bufsel][(half) * 8192 + wid * 512];                         \
    gld16(_s + o1, _d);                                                        \
    gld16(_s + o2, _d + 4096);                                                 \
  }
#define STAGEB(bufsel, half, tt)                                               \
  {                                                                            \
    const bf16* _s = Bb + (size_t)(half) * 128 * K + (size_t)(tt) * 64;        \
    bf16* _d = &lB[bufsel][(half) * 8192 + wid * 512];                         \
    gld16(_s + o1, _d);                                                        \
    gld16(_s + o2, _d + 4096);                                                 \
  }

#define WAIT_LGKM0                                                             \
  do {                                                                         \
    asm volatile("s_waitcnt lgkmcnt(0)" ::: "memory");                         \
    __builtin_amdgcn_sched_barrier(0);                                         \
  } while (0)
#define WAIT_VM(n) asm volatile("s_waitcnt vmcnt(" #n ")" ::: "memory")

  // frag-read swizzled 16B-column offsets (bytes) for ks=0,1
  const int csw0 = ((quad ^ (l15 & 7)) << 4);
  const int csw1 = (((4 | quad) ^ (l15 & 7)) << 4);

  f32x4 acc[8][4];
#pragma unroll
  for (int i = 0; i < 8; ++i)
#pragma unroll
    for (int j = 0; j < 4; ++j) acc[i][j] = (f32x4)0.f;

  short8 a[4][2], b23[2][2], b01A[2][2], b01B[2][2];

  // Prologue: stage tiles 0,1 in full; wait tile0; pre-read b01 of tile0.
  STAGEA(0, 0, 0); STAGEA(0, 1, 0);
  STAGEB(0, 0, 0); STAGEB(0, 1, 0);
  if (NT > 1) {
    STAGEA(1, 0, 1); STAGEA(1, 1, 1);
    STAGEB(1, 0, 1); STAGEB(1, 1, 1);
    WAIT_VM(8);                        // tile0's 8 loads landed
  } else {
    WAIT_VM(0);
  }
  __builtin_amdgcn_s_barrier();
#pragma unroll
  for (int n = 0; n < 2; ++n) {
    const char* p = (const char*)lB[0] + (size_t)(wc * 64 + n * 16 + l15) * 128;
    b01A[n][0] = *(const short8*)(p + csw0);
    b01A[n][1] = *(const short8*)(p + csw1);
  }

#define KTILE(T, B01U, B01L)                                                   \
  do {                                                                         \
    const int _t = (T);                                                        \
    const bf16* Al = lA[_t % 3];                                               \
    const bf16* Bl = lB[_t & 1];                                               \
    const bf16* Bln = lB[(_t + 1) & 1];                                        \
    const bool stg = (_t + 2 < NT);                                            \
    const bool nxt = (_t + 1 < NT);                                            \
    /* ---- ph1: read a03; stage A[t+2]h0; drain; MFMA a03 x b01cur */         \
    _Pragma("unroll") for (int mi = 0; mi < 4; ++mi) {                         \
      const char* p = (const char*)Al + (size_t)(wr * 128 + mi * 16 + l15) * 128; \
      a[mi][0] = *(const short8*)(p + csw0);                                   \
      a[mi][1] = *(const short8*)(p + csw1);                                   \
    }                                                                          \
    if (stg) STAGEA((_t + 2) % 3, 0, _t + 2);                                  \
    WAIT_LGKM0;                                                                \
    __builtin_amdgcn_s_setprio(1);                                             \
    _Pragma("unroll") for (int mi = 0; mi < 4; ++mi)                           \
      _Pragma("unroll") for (int n = 0; n < 2; ++n) {                          \
        acc[mi][n] = mfma16(a[mi][0], B01U[n][0], acc[mi][n]);                 \
        acc[mi][n] = mfma16(a[mi][1], B01U[n][1], acc[mi][n]);                 \
      }                                                                        \
    __builtin_amdgcn_s_setprio(0);                                             \
    /* ---- ph2: read b23; stage A[t+2]h1; drain; MFMA a03 x b23 */            \
    _Pragma("unroll") for (int n = 0; n < 2; ++n) {                            \
      const char* p = (const char*)Bl + (size_t)(wc * 64 + (2 + n) * 16 + l15) * 128; \
      b23[n][0] = *(const short8*)(p + csw0);                                  \
      b23[n][1] = *(const short8*)(p + csw1);                                  \
    }                                                                          \
    if (stg) STAGEA((_t + 2) % 3, 1, _t + 2);                                  \
    WAIT_LGKM0;                                                                \
    __builtin_amdgcn_s_setprio(1);                                             \
    _Pragma("unroll") for (int mi = 0; mi < 4; ++mi)                           \
      _Pragma("unroll") for (int n = 0; n < 2; ++n) {                          \
        acc[mi][2 + n] = mfma16(a[mi][0], b23[n][0], acc[mi][2 + n]);          \
        acc[mi][2 + n] = mfma16(a[mi][1], b23[n][1], acc[mi][2 + n]);          \
      }                                                                        \
    __builtin_amdgcn_s_setprio(0);                                             \
    /* ---- ph3: read a47 (reuse a[]); stage B[t+2]h0; vmcnt(6); BARRIER;      \
            drain; MFMA a47 x b23 */                                           \
    _Pragma("unroll") for (int mi = 0; mi < 4; ++mi) {                         \
      const char* p = (const char*)Al + (size_t)(wr * 128 + 64 + mi * 16 + l15) * 128; \
      a[mi][0] = *(const short8*)(p + csw0);                                   \
      a[mi][1] = *(const short8*)(p + csw1);                                   \
    }                                                                          \
    if (stg) STAGEB(_t & 1, 0, _t + 2);                                        \
    if (stg) { WAIT_VM(6); } else { WAIT_VM(0); }                              \
    __builtin_amdgcn_s_barrier();                                              \
    WAIT_LGKM0;                                                                \
    __builtin_amdgcn_s_setprio(1);                                             \
    _Pragma("unroll") for (int mi = 0; mi < 4; ++mi)                           \
      _Pragma("unroll") for (int n = 0; n < 2; ++n) {                          \
        acc[4 + mi][2 + n] = mfma16(a[mi][0], b23[n][0], acc[4 + mi][2 + n]);  \
        acc[4 + mi][2 + n] = mfma16(a[mi][1], b23[n][1], acc[4 + mi][2 + n]);  \
      }                                                                        \
    __builtin_amdgcn_s_setprio(0);                                             \
    /* ---- ph4: read b01next (B[t+1] published by ph3 vmcnt+barrier);         \
            stage B[t+2]h1; MFMA a47 x b01cur (register-only); BARRIER */      \
    if (nxt) {                                                                 \
      _Pragma("unroll") for (int n = 0; n < 2; ++n) {                          \
        const char* p = (const char*)Bln + (size_t)(wc * 64 + n * 16 + l15) * 128; \
        B01L[n][0] = *(const short8*)(p + csw0);                               \
        B01L[n][1] = *(const short8*)(p + csw1);                               \
      }                                                                        \
    }                                                                          \
    if (stg) STAGEB(_t & 1, 1, _t + 2);                                        \
    __builtin_amdgcn_s_setprio(1);                                             \
    _Pragma("unroll") for (int mi = 0; mi < 4; ++mi)                           \
      _Pragma("unroll") for (int n = 0; n < 2; ++n) {                          \
        acc[4 + mi][n] = mfma16(a[mi][0], B01U[n][0], acc[4 + mi][n]);         \
        acc[4 + mi][n] = mfma16(a[mi][1], B01U[n][1], acc[4 + mi][n]);         \
      }                                                                        \
    __builtin_amdgcn_s_setprio(0);                                             \
    __builtin_amdgcn_s_barrier();                                              \
  } while (0)

  for (int t = 0; t < NT; t += 2) {
    KTILE(t, b01A, b01B);
    if (t + 1 < NT) KTILE(t + 1, b01B, b01A);
  }
#undef KTILE
#undef STAGEA
#undef STAGEB
#undef WAIT_LGKM0
#undef WAIT_VM

  // Epilogue: C += bias
  const int crow = m0 + wr * 128 + quad * 4;
  const int ccol = n0 + wc * 64 + l15;
#pragma unroll
  for (int n = 0; n < 4; ++n) {
    const float bv = bf2f(bias[ccol + n * 16]);
#pragma unroll
    for (int mi = 0; mi < 8; ++mi) {
      const int rb = crow + mi * 16;
#pragma unroll
      for (int r = 0; r < 4; ++r)
        C[(size_t)(rb + r) * N + ccol + n * 16] = f2bf(acc[mi][n][r] + bv);
    }
  }
}

// ---------------------------------------------------------------------------
// RoPE + repack: qkv[t][7680] -> Qr/Kr [bh][s][80]; Q pre-scaled by 1/sqrt(80)
// ---------------------------------------------------------------------------
__global__ __launch_bounds__(256) void rope_kernel(
    const bf16* __restrict__ qkv, const bf16* __restrict__ cosb,
    const bf16* __restrict__ sinb, bf16* __restrict__ Qr, bf16* __restrict__ Kr)
{
  const int t = blockIdx.x;
  const int b = t >> 11;
  const int s = t & 2047;
  const float qscale = 0.11180339887498949f;

  __shared__ float cs[20], sn[20];
  if (threadIdx.x < 20) cs[threadIdx.x] = bf2f(cosb[t * 20 + threadIdx.x]);
  if (threadIdx.x >= 32 && threadIdx.x < 52)
    sn[threadIdx.x - 32] = bf2f(sinb[t * 20 + (threadIdx.x - 32)]);
  __syncthreads();

  const bf16* qrow = qkv + (size_t)t * QKVN;
  const bf16* krow = qrow + HID;

  for (int idx = threadIdx.x; idx < HID; idx += 256) {
    const int h = idx / HD, d = idx % HD;
    const size_t off = ((size_t)(b * NH + h) * SEQ + s) * HD + d;
    float q, k;
    if (d < 20) {
      q = bf2f(qrow[h * HD + d]) * cs[d] - bf2f(qrow[h * HD + d + 20]) * sn[d];
      k = bf2f(krow[h * HD + d]) * cs[d] - bf2f(krow[h * HD + d + 20]) * sn[d];
    } else if (d < 40) {
      q = bf2f(qrow[h * HD + d - 20]) * sn[d - 20] + bf2f(qrow[h * HD + d]) * cs[d - 20];
      k = bf2f(krow[h * HD + d - 20]) * sn[d - 20] + bf2f(krow[h * HD + d]) * cs[d - 20];
    } else {
      q = bf2f(qrow[h * HD + d]);
      k = bf2f(krow[h * HD + d]);
    }
    Qr[off] = f2bf(q * qscale);
    Kr[off] = f2bf(k);
  }
}

// ---------------------------------------------------------------------------
// V transpose: qkv V-part [t][h*80+d] -> Vt [bh][d][s]
// ---------------------------------------------------------------------------
__global__ __launch_bounds__(256) void vtrans_kernel(
    const bf16* __restrict__ qkv, bf16* __restrict__ Vt)
{
  const int bh = blockIdx.x;
  const int s0 = blockIdx.y * 64;
  const int b = bh >> 5, h = bh & 31;
  __shared__ bf16 tile[64][81];

  for (int e = threadIdx.x; e < 64 * HD; e += 256) {
    const int r = e / HD, d = e % HD;
    tile[r][d] = qkv[(size_t)(b * SEQ + s0 + r) * QKVN + 2 * HID + h * HD + d];
  }
  __syncthreads();
  for (int e = threadIdx.x; e < 64 * HD; e += 256) {
    const int d = e >> 6, r = e & 63;
    Vt[((size_t)bh * HD + d) * SEQ + s0 + r] = tile[r][d];
  }
}

// ---------------------------------------------------------------------------
// Flash attention v4, causal. Block = 128 q-rows (4 waves x 2 frags of 16),
// kv-step 64. Staging via global_load_lds (1424 contiguous 16B chunks: K tile
// [64][88] + V tile rows 0..79 of [96][72]); V rows 80..95 = ones (denominator
// accumulated as PV's 6th d-tile). QK^T computed TRANSPOSED (K as A-operand,
// Q as B-operand -> S^T C-layout: kv=quad*4+r, qrow=l15) so softmax rows are
// per-lane and P^T is written with packed b64 stores straight into A-layout.
// ---------------------------------------------------------------------------
__global__ __launch_bounds__(256, 3) void attn_kernel(
    const bf16* __restrict__ Qr, const bf16* __restrict__ Kr,
    const bf16* __restrict__ Vt, bf16* __restrict__ O)
{
  // XCD-aware decode: 16 q-blocks of a bh share an XCD; heavy qblk first
  const int raw  = blockIdx.x;          // 0..1023
  const int slot = raw >> 3;
  const int qblk = 15 - (slot & 15);
  const int bh   = ((slot >> 4) << 3) + (raw & 7);

  const int tid  = threadIdx.x;
  const int wave = tid >> 6;
  const int lane = tid & 63;
  const int quad = lane >> 4;
  const int l15  = lane & 15;
  const int qbase = qblk * 128;

  // staging region: 1424 chunks *16B = kt[64][88] then vt rows 0..79 of [96][72]
  // (kt col-pad 80..87 and vt col-pad 64..71 are garbage chunks, never read
  //  or killed by zero operands); vt rows 80..95 = ones, init'd once.
  __shared__ __align__(16) bf16 stage[12544];
  __shared__ __align__(16) bf16 pt[4 * 2 * 1152];   // per wave x frag: [16][72] P^T

  bf16* kt = stage;            // 64*88
  bf16* vt = stage + 5632;     // 96*72

  if (tid < 144) {
    const unsigned one2 = 0x3F803F80u;  // two bf16 1.0
    *(uint4*)&vt[5760 + tid * 8] = (uint4){one2, one2, one2, one2};
  }

  // staging chunk -> static global byte offset (c==pad chunk -> row start)
  int goff[6];
#pragma unroll
  for (int it = 0; it < 6; it++) {
    const int j = tid + it * 256;
    if (j < 704) {                       // K: row r (160B) as 10 chunks + 1 pad
      const int r = j / 11; int c = j - 11 * r; if (c > 9) c = 0;
      goff[it] = r * 160 + c * 16;
    } else {                             // V: row r (128B) as 8 chunks + 1 pad
      const int j2 = j - 704;
      const int r = j2 / 9; int c = j2 - 9 * r; if (c > 7) c = 0;
      goff[it] = r * 4096 + c * 16;
    }
  }

  // Q fragments: 2 frags x 3 K-chunks, resident (scale pre-folded at RoPE)
  short8 aq[2][3];
#pragma unroll
  for (int f = 0; f < 2; f++) {
    const bf16* Qb = Qr + ((size_t)bh * SEQ + qbase + f * 64 + wave * 16 + l15) * HD + quad * 8;
    aq[f][0] = *(const short8*)(Qb);
    aq[f][1] = *(const short8*)(Qb + 32);
    aq[f][2] = *(const short8*)(Qb + 64);   // quad>=2 reads past row end (mapped)
    if (quad >= 2) aq[f][2] = (short8)0;    // exact zero pad d>=80
  }

  f32x4 o[2][6];      // [frag][5 data d-tiles + 1 denominator tile]
#pragma unroll
  for (int f = 0; f < 2; f++)
    for (int nt = 0; nt < 6; nt++) o[f][nt] = (f32x4)0.f;
  float m_i[2] = {-3e38f, -3e38f};   // per-lane row-max state for qrow=l15

  const char* Kb8 = (const char*)(Kr + (size_t)bh * SEQ * HD);
  const char* Vb8 = (const char*)(Vt + (size_t)bh * HD * SEQ);
  const int nsteps = 2 * qblk + 2;
  const int rmax0 = qbase + wave * 16 + 15;   // frag0 last row (frag1 always active)

  for (int step = 0; step < nsteps; step++) {
    const int kvo = step * 64;
    const bool act0 = (kvo <= rmax0);

    __syncthreads();   // prior step's LDS reads done (also covers ones-init)
    {
      const char* kb = Kb8 + kvo * 160;
      const char* vb = Vb8 + kvo * 2;
#pragma unroll
      for (int it = 0; it < 6; it++) {
        const int j = tid + it * 256;
        if (j < 1424) {
          bf16* ldsb = stage + (it * 256 + wave * 64) * 8;   // wave-uniform
          gld16((j < 704) ? (kb + goff[it]) : (vb + goff[it]), ldsb);
        }
      }
    }
    __syncthreads();   // staging landed

    // S^T = K Q^T : C-layout kv=quad*4+r (per tile), qrow=l15
    f32x4 sv[2][4];
#pragma unroll
    for (int nt = 0; nt < 4; nt++) {
      const bf16* kr = &kt[(nt * 16 + l15) * 88 + quad * 8];
      short8 b0 = *(const short8*)(kr);
      short8 b1 = *(const short8*)(kr + 32);
      short8 b2 = *(const short8*)(kr + 64);  // k>=80 garbage killed by aq[..][2]=0
      if (act0) {
        f32x4 s = mfma16(b0, aq[0][0], (f32x4)0.f);
        s = mfma16(b1, aq[0][1], s);
        sv[0][nt] = mfma16(b2, aq[0][2], s);
      }
      f32x4 s1 = mfma16(b0, aq[1][0], (f32x4)0.f);
      s1 = mfma16(b1, aq[1][1], s1);
      sv[1][nt] = mfma16(b2, aq[1][2], s1);
    }

    // online softmax per frag; per lane: 16 values of qrow=l15
#pragma unroll
    for (int f = 0; f < 2; f++) {
      if (f == 0 && !act0) continue;
      const int mrel = qbase + f * 64 + wave * 16 - kvo;   // wave-uniform
      if (mrel < 63) {
        const int qrel = mrel + l15;
#pragma unroll
        for (int nt = 0; nt < 4; nt++) {
          f32x4 t = sv[f][nt];
#pragma unroll
          for (int r = 0; r < 4; r++)
            t[r] = (nt * 16 + quad * 4 + r <= qrel) ? t[r] : -3e38f;
          sv[f][nt] = t;
        }
      }
      float mx = fmaxf(fmaxf(sv[f][0][0], sv[f][0][1]), fmaxf(sv[f][0][2], sv[f][0][3]));
#pragma unroll
      for (int nt = 1; nt < 4; nt++)
        mx = fmaxf(mx, fmaxf(fmaxf(sv[f][nt][0], sv[f][nt][1]),
                             fmaxf(sv[f][nt][2], sv[f][nt][3])));
      mx = fmaxf(mx, __shfl_xor(mx, 16, 64));
      mx = fmaxf(mx, __shfl_xor(mx, 32, 64));
      const float mnew = fmaxf(m_i[f], mx);
      const float alpha = __expf(m_i[f] - mnew);
      m_i[f] = mnew;

      bf16* ptw = pt + (wave * 2 + f) * 1152;
#pragma unroll
      for (int nt = 0; nt < 4; nt++) {
        __align__(8) bf16 p4[4];
#pragma unroll
        for (int r = 0; r < 4; r++) p4[r] = f2bf(__expf(sv[f][nt][r] - mnew));
        *(unsigned long long*)&ptw[l15 * 72 + nt * 16 + quad * 4] =
            *(const unsigned long long*)p4;
      }
      // broadcast alpha to O's C-layout rows (quad*4+r) via lanes 0..15
      float av[4];
#pragma unroll
      for (int r = 0; r < 4; r++) av[r] = __shfl(alpha, quad * 4 + r, 64);
#pragma unroll
      for (int nt = 0; nt < 6; nt++) {
        f32x4 t = o[f][nt];
        t[0] *= av[0]; t[1] *= av[1]; t[2] *= av[2]; t[3] *= av[3];
        o[f][nt] = t;
      }
    }

    asm volatile("s_waitcnt lgkmcnt(0)" ::: "memory");   // P^T writes landed (per-wave)
    short8 pa00 = (short8)0, pa01 = (short8)0, pa10, pa11;
    {
      const bf16* p0 = pt + (wave * 2 + 0) * 1152 + l15 * 72 + quad * 8;
      const bf16* p1 = pt + (wave * 2 + 1) * 1152 + l15 * 72 + quad * 8;
      if (act0) { pa00 = *(const short8*)p0; pa01 = *(const short8*)(p0 + 32); }
      pa10 = *(const short8*)p1; pa11 = *(const short8*)(p1 + 32);
    }
    // O += P V : 6 d-tiles (tile 5 = denominator), vt reads shared by frags
#pragma unroll
    for (int nt = 0; nt < 6; nt++) {
      const bf16* vr = &vt[(nt * 16 + l15) * 72 + quad * 8];
      short8 v0 = *(const short8*)(vr);
      short8 v1 = *(const short8*)(vr + 32);
      if (act0) {
        o[0][nt] = mfma16(pa00, v0, o[0][nt]);
        o[0][nt] = mfma16(pa01, v1, o[0][nt]);
      }
      o[1][nt] = mfma16(pa10, v0, o[1][nt]);
      o[1][nt] = mfma16(pa11, v1, o[1][nt]);
    }
  }

  // epilogue: out[t][h*80+d] = O / l
  const int b = bh >> 5, h = bh & 31;
#pragma unroll
  for (int f = 0; f < 2; f++)
#pragma unroll
    for (int r = 0; r < 4; r++) {
      const float inv = 1.0f / o[f][5][r];
      const int trow = b * SEQ + qbase + f * 64 + wave * 16 + quad * 4 + r;
#pragma unroll
      for (int nt = 0; nt < 5; nt++)
        O[(size_t)trow * HID + h * HD + nt * 16 + l15] = f2bf(o[f][nt][r] * inv);
    }
}

// ---------------------------------------------------------------------------
extern "C" void kernel_launch(void* const* d_in, const int* in_sizes, int n_in,
                              void* d_out, int out_size, void* d_ws, size_t ws_size,
                              hipStream_t stream) {
  (void)in_sizes; (void)n_in; (void)ws_size;
  char* wsb = (char*)d_ws;

  int*  flag   = (int*) (wsb + 0);
  bf16* cos_c  = (bf16*)(wsb + 1024);
  bf16* sin_c  = (bf16*)(wsb + 165888);
  bf16* bqkv_c = (bf16*)(wsb + 329728);
  bf16* bo_c   = (bf16*)(wsb + 345088);
  bf16* wo_c   = (bf16*)(wsb + 1048576);         // -> 14,155,776
  bf16* qkv    = (bf16*)(wsb + 14155776);        // -> 77,070,336
  bf16* hid_c  = (bf16*)(wsb + 77070336);        // -> 98,041,856
  bf16* wqkv_c = (bf16*)(wsb + 98041856);        // -> 137,363,456
  bf16* Qr     = (bf16*)(wsb + 77070336);        // over hid_c (dead post-GEMM1)
  bf16* Kr     = (bf16*)(wsb + 98041856);        // over wqkv_c (dead post-GEMM1)
  bf16* Vt     = (bf16*)(wsb + 119013376);       // -> 139,984,896
  bf16* attn   = (bf16*)(wsb + 14155776);        // over qkv (dead)
  bf16* obuf   = (bf16*)(wsb + 35127296);        // over qkv+21M

  detect_kernel<<<1, 256, 0, stream>>>((const unsigned short*)d_in[0], flag);
  convert_kernel<<<1024, 256, 0, stream>>>(d_in[0], hid_c,  TTOT * HID / 8, flag);
  convert_kernel<<<1024, 256, 0, stream>>>(d_in[1], wqkv_c, QKVN * HID / 8, flag);
  convert_kernel<<<4,    256, 0, stream>>>(d_in[2], bqkv_c, QKVN / 8,       flag);
  convert_kernel<<<1024, 256, 0, stream>>>(d_in[3], wo_c,   HID * HID / 8,  flag);
  convert_kernel<<<2,    256, 0, stream>>>(d_in[4], bo_c,   HID / 8,        flag);
  convert_kernel<<<40,   256, 0, stream>>>(d_in[5], cos_c,  TTOT * 20 / 8,  flag);
  convert_kernel<<<40,   256, 0, stream>>>(d_in[6], sin_c,  TTOT * 20 / 8,  flag);

  gemm256_bias<<<dim3((TTOT / 256) * (QKVN / 256)), 512, 0, stream>>>(
      hid_c, wqkv_c, bqkv_c, qkv, TTOT, QKVN, HID);
  rope_kernel<<<dim3(TTOT), 256, 0, stream>>>(qkv, cos_c, sin_c, Qr, Kr);
  vtrans_kernel<<<dim3(64, SEQ / 64), 256, 0, stream>>>(qkv, Vt);
  attn_kernel<<<dim3(1024), 256, 0, stream>>>(Qr, Kr, Vt, attn);
  gemm256_bias<<<dim3((TTOT / 256) * (HID / 256)), 512, 0, stream>>>(
      attn, wo_c, bo_c, obuf, TTOT, HID, HID);
  emit_kernel<<<1024, 256, 0, stream>>>(obuf, d_out, out_size / 8, flag);
}

// Round 6
// 554.418 us; speedup vs baseline: 1.4532x; 1.0672x over previous
//
#include <hip/hip_runtime.h>
#include <hip/hip_bf16.h>

// Problem constants
#define HID   2560
#define NH    32
#define HD    80      // head dim
#define SEQ   2048
#define TTOT  4096    // B*S
#define QKVN  7680    // 3*HID

typedef float  f32x4  __attribute__((ext_vector_type(4)));
typedef short  short8 __attribute__((ext_vector_type(8)));
typedef unsigned short us4 __attribute__((ext_vector_type(4)));
typedef __bf16 bf16x8 __attribute__((ext_vector_type(8)));
typedef __hip_bfloat16 bf16;

__device__ __forceinline__ float bf2f(bf16 h) { return __bfloat162float(h); }
__device__ __forceinline__ bf16  f2bf(float f) { return __float2bfloat16(f); }
__device__ __forceinline__ float us2f(unsigned short u) {
  unsigned int x = ((unsigned int)u) << 16;
  return __builtin_bit_cast(float, x);
}

__device__ __forceinline__ f32x4 mfma16(short8 a, short8 b, f32x4 c) {
  return __builtin_amdgcn_mfma_f32_16x16x32_bf16(
      __builtin_bit_cast(bf16x8, a), __builtin_bit_cast(bf16x8, b), c, 0, 0, 0);
}

// async global->LDS, 16B per lane: LDS dest = wave-uniform base + lane*16,
// global side is a per-lane gather.
typedef __attribute__((address_space(1))) const unsigned int as1_uint;
typedef __attribute__((address_space(3))) unsigned int       as3_uint;
__device__ __forceinline__ void gld16(const void* g, void* l) {
  __builtin_amdgcn_global_load_lds((as1_uint*)g, (as3_uint*)l, 16, 0, 0);
}

// ---------------------------------------------------------------------------
// Dtype detection (flag=1 -> inputs are f32; 0 -> bf16).
// ---------------------------------------------------------------------------
__global__ void detect_kernel(const unsigned short* __restrict__ hid, int* flag) {
  const int tid = threadIdx.x;  // 256
  const unsigned short u = hid[2 * (tid * 997)];
  const int e = (u >> 7) & 0xFF;
  const int sane = (u == 0 || (e >= 0x60 && e <= 0x8A)) ? 1 : 0;
  __shared__ int cnt;
  if (tid == 0) cnt = 0;
  __syncthreads();
  atomicAdd(&cnt, sane);
  __syncthreads();
  if (tid == 0) *flag = (cnt < 160) ? 1 : 0;
}

// Normalize float input to bf16, 8 elems/thread. n8 = n/8.
__global__ void convert_kernel(const void* __restrict__ src, bf16* __restrict__ dst,
                               int n8, const int* __restrict__ flag) {
  const bool isf32 = (*flag != 0);
  for (int i = blockIdx.x * 256 + threadIdx.x; i < n8; i += gridDim.x * 256) {
    if (isf32) {
      const float4* s = (const float4*)src;
      float4 a = s[2 * i], b = s[2 * i + 1];
      __align__(16) bf16 o8[8] = {f2bf(a.x), f2bf(a.y), f2bf(a.z), f2bf(a.w),
                                  f2bf(b.x), f2bf(b.y), f2bf(b.z), f2bf(b.w)};
      *(uint4*)(dst + 8 * i) = *(const uint4*)o8;
    } else {
      *(uint4*)(dst + 8 * i) = ((const uint4*)src)[i];
    }
  }
}

// Emit output in true dtype. n8 = n/8.
__global__ void emit_kernel(const bf16* __restrict__ src, void* __restrict__ dst,
                            int n8, const int* __restrict__ flag) {
  const bool isf32 = (*flag != 0);
  for (int i = blockIdx.x * 256 + threadIdx.x; i < n8; i += gridDim.x * 256) {
    uint4 v = *(const uint4*)(src + 8 * i);
    if (isf32) {
      const bf16* b = (const bf16*)&v;
      float4* d = (float4*)dst;
      d[2 * i]     = make_float4(bf2f(b[0]), bf2f(b[1]), bf2f(b[2]), bf2f(b[3]));
      d[2 * i + 1] = make_float4(bf2f(b[4]), bf2f(b[5]), bf2f(b[6]), bf2f(b[7]));
    } else {
      ((uint4*)dst)[i] = v;
    }
  }
}

// ---------------------------------------------------------------------------
// GEMM, 256x256 tile / BK=64 / 8 waves. UNPINNED 2-region schedule:
// R1-R5 all plateaued at MfmaUtil 37%; common invariant was the hand-inserted
// lgkmcnt(0)+sched_barrier(0) before every MFMA cluster, which forces a full
// 8-wave LDS queue drain (~500cy) before any MFMA can issue and blocks the
// compiler's fine-grained counted-lgkmcnt interleave (m97 note; m141: pinning
// regresses). Here the ds_reads are plain C++ loads and the interior carries
// NO waits/sched_barriers: the compiler emits counted lgkmcnt per consumer
// and interleaves reads/stages/MFMAs. Only what it cannot derive is kept:
//
//   region 1: read a03,b23; stage A[t+2](h0,h1); MFMA a03 x {b01cur, b23}
//   mid:      lgkm(0)        [own reads done -> B-buffer WAR safe]
//             vmcnt(4)       [FIFO: A(t+1)4,B(t+1)4,A(t+2)4 -> drain t+1's 8]
//             barrier        [publish A(t+1),B(t+1) to all waves]
//   region 2: read a47, b01next(from lB[(t+1)&1]); stage B[t+2](h0,h1);
//             MFMA a47 x {b23, b01cur}
//   end:      lgkm(0)        [a47 reads done -> A-buffer WAR safe]; barrier
//
// WAR proofs: STAGEA(t+2) writes lA[(t+2)%3]=lA[(t-1)%3], whose reads ended
// before t-1's end lgkm(0)+barrier. STAGEB(t+2) writes lB[t&1], whose reads
// (b23 this tile, b01cur last tile) ended before this mid / last end barrier.
// b01 ping-pong (b01A/b01B, static indexing) via 2x-unrolled tile loop.
// A triple-buffered, B double-buffered (160 KiB LDS), depth-2 staging.
// Requires M%256==0, N%256==0, K%64==0.
//
// LDS swizzle: phys_byte = logical_byte ^ ((row&7)<<4) applied on the global
// source at stage time + on the ds_read address (both-sides involution).
// ---------------------------------------------------------------------------
__global__ __launch_bounds__(512, 2) void gemm256_bias(
    const bf16* __restrict__ A, const bf16* __restrict__ B,
    const bf16* __restrict__ bias, bf16* __restrict__ C,
    int M, int N, int K)
{
  __shared__ __align__(16) bf16 lA[3][16384];   // 3 x 256rows x 64cols
  __shared__ __align__(16) bf16 lB[2][16384];   // 2 x 256rows x 64cols

  const int tid  = threadIdx.x;
  const int wid  = tid >> 6;
  const int lane = tid & 63;
  const int quad = lane >> 4;
  const int l15  = lane & 15;
  const int wr   = wid >> 2;   // 0..1 -> 128 rows each
  const int wc   = wid & 3;    // 0..3 -> 64 cols each

  // bijective XCD-aware block swizzle (m204)
  int wgid;
  {
    const int nwg = gridDim.x;
    const int q = nwg >> 3, r = nwg & 7;
    const int xcd = blockIdx.x & 7, lin = blockIdx.x >> 3;
    wgid = (xcd < r ? xcd * (q + 1) : r * (q + 1) + (xcd - r) * q) + lin;
  }
  const int gx = M >> 8;
  const int m0 = (wgid % gx) << 8;
  const int n0 = (wgid / gx) << 8;

  const int NT = K >> 6;   // K-tiles of 64

  // Staging geometry: half-tile = 128 rows x 64 cols = 1024 chunks of 16B.
  // Thread handles phys chunks tid and tid+512 (same swizzled col, +64 rows).
  const int rr   = tid >> 3;                               // phys row 0..63
  const int cbyt = ((tid & 7) << 4) ^ ((rr & 7) << 4);     // logical col byte
  const size_t o1 = (size_t)rr * K + (cbyt >> 1);
  const size_t o2 = o1 + (size_t)64 * K;

  const bf16* Ab = A + (size_t)m0 * K;
  const bf16* Bb = B + (size_t)n0 * K;

#define STAGEA(bufsel, half, tt)                                               \
  {                                                                            \
    const bf16* _s = Ab + (size_t)(half) * 128 * K + (size_t)(tt) * 64;        \
    bf16* _d = &lA[bufsel][(half) * 8192 + wid * 512];                         \
    gld16(_s + o1, _d);                                                        \
    gld16(_s + o2, _d + 4096);                                                 \
  }
#define STAGEB(bufsel, half, tt)                                               \
  {                                                                            \
    const bf16* _s = Bb + (size_t)(half) * 128 * K + (size_t)(tt) * 64;        \
    bf16* _d = &lB[bufsel][(half) * 8192 + wid * 512];                         \
    gld16(_s + o1, _d);                                                        \
    gld16(_s + o2, _d + 4096);                                                 \
  }

  // frag-read swizzled 16B-column offsets (bytes) for ks=0,1
  const int csw0 = ((quad ^ (l15 & 7)) << 4);
  const int csw1 = (((4 | quad) ^ (l15 & 7)) << 4);

  f32x4 acc[8][4];
#pragma unroll
  for (int i = 0; i < 8; ++i)
#pragma unroll
    for (int j = 0; j < 4; ++j) acc[i][j] = (f32x4)0.f;

  short8 a[4][2], b23[2][2], b01A[2][2], b01B[2][2];

  // Prologue: stage tiles 0,1 in full; wait tile0; pre-read b01 of tile0.
  STAGEA(0, 0, 0); STAGEA(0, 1, 0);
  STAGEB(0, 0, 0); STAGEB(0, 1, 0);
  if (NT > 1) {
    STAGEA(1, 0, 1); STAGEA(1, 1, 1);
    STAGEB(1, 0, 1); STAGEB(1, 1, 1);
    asm volatile("s_waitcnt vmcnt(8)" ::: "memory");   // tile0 landed
  } else {
    asm volatile("s_waitcnt vmcnt(0)" ::: "memory");
  }
  __builtin_amdgcn_s_barrier();
#pragma unroll
  for (int n = 0; n < 2; ++n) {
    const char* p = (const char*)lB[0] + (size_t)(wc * 64 + n * 16 + l15) * 128;
    b01A[n][0] = *(const short8*)(p + csw0);
    b01A[n][1] = *(const short8*)(p + csw1);
  }

#define KTILE(T, B01U, B01L)                                                   \
  do {                                                                         \
    const int _t = (T);                                                        \
    const bf16* Al = lA[_t % 3];                                               \
    const bf16* Bl = lB[_t & 1];                                               \
    const bf16* Bln = lB[(_t + 1) & 1];                                        \
    const bool stg = (_t + 2 < NT);                                            \
    const bool nxt = (_t + 1 < NT);                                            \
    /* ---- region 1 (no explicit waits: compiler emits counted lgkmcnt) */    \
    _Pragma("unroll") for (int mi = 0; mi < 4; ++mi) {                         \
      const char* p = (const char*)Al + (size_t)(wr * 128 + mi * 16 + l15) * 128; \
      a[mi][0] = *(const short8*)(p + csw0);                                   \
      a[mi][1] = *(const short8*)(p + csw1);                                   \
    }                                                                          \
    _Pragma("unroll") for (int n = 0; n < 2; ++n) {                            \
      const char* p = (const char*)Bl + (size_t)(wc * 64 + (2 + n) * 16 + l15) * 128; \
      b23[n][0] = *(const short8*)(p + csw0);                                  \
      b23[n][1] = *(const short8*)(p + csw1);                                  \
    }                                                                          \
    if (stg) { STAGEA((_t + 2) % 3, 0, _t + 2); STAGEA((_t + 2) % 3, 1, _t + 2); } \
    _Pragma("unroll") for (int mi = 0; mi < 4; ++mi)                           \
      _Pragma("unroll") for (int n = 0; n < 2; ++n) {                          \
        acc[mi][n] = mfma16(a[mi][0], B01U[n][0], acc[mi][n]);                 \
        acc[mi][n] = mfma16(a[mi][1], B01U[n][1], acc[mi][n]);                 \
      }                                                                        \
    _Pragma("unroll") for (int mi = 0; mi < 4; ++mi)                           \
      _Pragma("unroll") for (int n = 0; n < 2; ++n) {                          \
        acc[mi][2 + n] = mfma16(a[mi][0], b23[n][0], acc[mi][2 + n]);          \
        acc[mi][2 + n] = mfma16(a[mi][1], b23[n][1], acc[mi][2 + n]);          \
      }                                                                        \
    /* ---- mid checkpoint: own reads done; t+1's stages landed; publish */    \
    asm volatile("s_waitcnt lgkmcnt(0)" ::: "memory");                         \
    if (stg) { asm volatile("s_waitcnt vmcnt(4)" ::: "memory"); }              \
    else     { asm volatile("s_waitcnt vmcnt(0)" ::: "memory"); }              \
    __builtin_amdgcn_s_barrier();                                              \
    /* ---- region 2 */                                                        \
    _Pragma("unroll") for (int mi = 0; mi < 4; ++mi) {                         \
      const char* p = (const char*)Al + (size_t)(wr * 128 + 64 + mi * 16 + l15) * 128; \
      a[mi][0] = *(const short8*)(p + csw0);                                   \
      a[mi][1] = *(const short8*)(p + csw1);                                   \
    }                                                                          \
    if (nxt) {                                                                 \
      _Pragma("unroll") for (int n = 0; n < 2; ++n) {                          \
        const char* p = (const char*)Bln + (size_t)(wc * 64 + n * 16 + l15) * 128; \
        B01L[n][0] = *(const short8*)(p + csw0);                               \
        B01L[n][1] = *(const short8*)(p + csw1);                               \
      }                                                                        \
    }                                                                          \
    if (stg) { STAGEB(_t & 1, 0, _t + 2); STAGEB(_t & 1, 1, _t + 2); }         \
    _Pragma("unroll") for (int mi = 0; mi < 4; ++mi)                           \
      _Pragma("unroll") for (int n = 0; n < 2; ++n) {                          \
        acc[4 + mi][2 + n] = mfma16(a[mi][0], b23[n][0], acc[4 + mi][2 + n]);  \
        acc[4 + mi][2 + n] = mfma16(a[mi][1], b23[n][1], acc[4 + mi][2 + n]);  \
      }                                                                        \
    _Pragma("unroll") for (int mi = 0; mi < 4; ++mi)                           \
      _Pragma("unroll") for (int n = 0; n < 2; ++n) {                          \
        acc[4 + mi][n] = mfma16(a[mi][0], B01U[n][0], acc[4 + mi][n]);         \
        acc[4 + mi][n] = mfma16(a[mi][1], B01U[n][1], acc[4 + mi][n]);         \
      }                                                                        \
    /* ---- tile end: a47/b01next reads done -> A-buffer WAR safe */           \
    asm volatile("s_waitcnt lgkmcnt(0)" ::: "memory");                         \
    __builtin_amdgcn_s_barrier();                                              \
  } while (0)

  for (int t = 0; t < NT; t += 2) {
    KTILE(t, b01A, b01B);
    if (t + 1 < NT) KTILE(t + 1, b01B, b01A);
  }
#undef KTILE
#undef STAGEA
#undef STAGEB

  // Epilogue: C += bias
  const int crow = m0 + wr * 128 + quad * 4;
  const int ccol = n0 + wc * 64 + l15;
#pragma unroll
  for (int n = 0; n < 4; ++n) {
    const float bv = bf2f(bias[ccol + n * 16]);
#pragma unroll
    for (int mi = 0; mi < 8; ++mi) {
      const int rb = crow + mi * 16;
#pragma unroll
      for (int r = 0; r < 4; ++r)
        C[(size_t)(rb + r) * N + ccol + n * 16] = f2bf(acc[mi][n][r] + bv);
    }
  }
}

// ---------------------------------------------------------------------------
// RoPE + repack, vectorized: qkv[t][7680] -> Qr/Kr [bh][s][80]; Q pre-scaled
// by 1/sqrt(80). 4-bf16 chunks (ROT/2=20 = 5 chunks -> rotation pairing is
// 4-aligned). 320 threads x 2 chunks = 640 chunks = HID/4 per token.
// ---------------------------------------------------------------------------
__global__ __launch_bounds__(320) void rope_kernel(
    const bf16* __restrict__ qkv, const bf16* __restrict__ cosb,
    const bf16* __restrict__ sinb, bf16* __restrict__ Qr, bf16* __restrict__ Kr)
{
  const int t = blockIdx.x;
  const int b = t >> 11;
  const int s = t & 2047;
  const float qscale = 0.11180339887498949f;

  __shared__ float cs[20], sn[20];
  if (threadIdx.x < 20) cs[threadIdx.x] = bf2f(cosb[t * 20 + threadIdx.x]);
  if (threadIdx.x >= 64 && threadIdx.x < 84)
    sn[threadIdx.x - 64] = bf2f(sinb[t * 20 + (threadIdx.x - 64)]);
  __syncthreads();

  const bf16* qrow = qkv + (size_t)t * QKVN;
  const bf16* krow = qrow + HID;

#pragma unroll
  for (int it = 0; it < 2; ++it) {
    const int ci = threadIdx.x + it * 320;      // 0..639
    const int h = ci / 20, c = ci % 20;
    const int d0 = c * 4;
    const bf16* qp = qrow + h * HD + d0;
    const bf16* kp = krow + h * HD + d0;
    const us4 qv = *(const us4*)qp;
    const us4 kv = *(const us4*)kp;
    float qo[4], ko[4];
    if (c < 5) {
      const us4 q2 = *(const us4*)(qp + 20);
      const us4 k2 = *(const us4*)(kp + 20);
#pragma unroll
      for (int j = 0; j < 4; ++j) {
        qo[j] = us2f(qv[j]) * cs[d0 + j] - us2f(q2[j]) * sn[d0 + j];
        ko[j] = us2f(kv[j]) * cs[d0 + j] - us2f(k2[j]) * sn[d0 + j];
      }
    } else if (c < 10) {
      const us4 q1 = *(const us4*)(qp - 20);
      const us4 k1 = *(const us4*)(kp - 20);
#pragma unroll
      for (int j = 0; j < 4; ++j) {
        qo[j] = us2f(q1[j]) * sn[d0 - 20 + j] + us2f(qv[j]) * cs[d0 - 20 + j];
        ko[j] = us2f(k1[j]) * sn[d0 - 20 + j] + us2f(kv[j]) * cs[d0 - 20 + j];
      }
    } else {
#pragma unroll
      for (int j = 0; j < 4; ++j) { qo[j] = us2f(qv[j]); ko[j] = us2f(kv[j]); }
    }
    const size_t off = ((size_t)(b * NH + h) * SEQ + s) * HD + d0;
    __align__(8) bf16 oq[4], ok[4];
#pragma unroll
    for (int j = 0; j < 4; ++j) {
      oq[j] = f2bf(qo[j] * qscale);
      ok[j] = f2bf(ko[j]);
    }
    *(unsigned long long*)(Qr + off) = *(const unsigned long long*)oq;
    *(unsigned long long*)(Kr + off) = *(const unsigned long long*)ok;
  }
}

// ---------------------------------------------------------------------------
// V transpose: qkv V-part [t][h*80+d] -> Vt [bh][d][s]
// ---------------------------------------------------------------------------
__global__ __launch_bounds__(256) void vtrans_kernel(
    const bf16* __restrict__ qkv, bf16* __restrict__ Vt)
{
  const int bh = blockIdx.x;
  const int s0 = blockIdx.y * 64;
  const int b = bh >> 5, h = bh & 31;
  __shared__ bf16 tile[64][81];

  for (int e = threadIdx.x; e < 64 * HD; e += 256) {
    const int r = e / HD, d = e % HD;
    tile[r][d] = qkv[(size_t)(b * SEQ + s0 + r) * QKVN + 2 * HID + h * HD + d];
  }
  __syncthreads();
  for (int e = threadIdx.x; e < 64 * HD; e += 256) {
    const int d = e >> 6, r = e & 63;
    Vt[((size_t)bh * HD + d) * SEQ + s0 + r] = tile[r][d];
  }
}

// ---------------------------------------------------------------------------
// Flash attention v4, causal. Block = 128 q-rows (4 waves x 2 frags of 16),
// kv-step 64. Staging via global_load_lds (1424 contiguous 16B chunks: K tile
// [64][88] + V tile rows 0..79 of [96][72]); V rows 80..95 = ones (denominator
// accumulated as PV's 6th d-tile). QK^T computed TRANSPOSED (K as A-operand,
// Q as B-operand -> S^T C-layout: kv=quad*4+r, qrow=l15) so softmax rows are
// per-lane and P^T is written with packed b64 stores straight into A-layout.
// ---------------------------------------------------------------------------
__global__ __launch_bounds__(256, 3) void attn_kernel(
    const bf16* __restrict__ Qr, const bf16* __restrict__ Kr,
    const bf16* __restrict__ Vt, bf16* __restrict__ O)
{
  // XCD-aware decode: 16 q-blocks of a bh share an XCD; heavy qblk first
  const int raw  = blockIdx.x;          // 0..1023
  const int slot = raw >> 3;
  const int qblk = 15 - (slot & 15);
  const int bh   = ((slot >> 4) << 3) + (raw & 7);

  const int tid  = threadIdx.x;
  const int wave = tid >> 6;
  const int lane = tid & 63;
  const int quad = lane >> 4;
  const int l15  = lane & 15;
  const int qbase = qblk * 128;

  // staging region: 1424 chunks *16B = kt[64][88] then vt rows 0..79 of [96][72]
  // (kt col-pad 80..87 and vt col-pad 64..71 are garbage chunks, never read
  //  or killed by zero operands); vt rows 80..95 = ones, init'd once.
  __shared__ __align__(16) bf16 stage[12544];
  __shared__ __align__(16) bf16 pt[4 * 2 * 1152];   // per wave x frag: [16][72] P^T

  bf16* kt = stage;            // 64*88
  bf16* vt = stage + 5632;     // 96*72

  if (tid < 144) {
    const unsigned one2 = 0x3F803F80u;  // two bf16 1.0
    *(uint4*)&vt[5760 + tid * 8] = (uint4){one2, one2, one2, one2};
  }

  // staging chunk -> static global byte offset (c==pad chunk -> row start)
  int goff[6];
#pragma unroll
  for (int it = 0; it < 6; it++) {
    const int j = tid + it * 256;
    if (j < 704) {                       // K: row r (160B) as 10 chunks + 1 pad
      const int r = j / 11; int c = j - 11 * r; if (c > 9) c = 0;
      goff[it] = r * 160 + c * 16;
    } else {                             // V: row r (128B) as 8 chunks + 1 pad
      const int j2 = j - 704;
      const int r = j2 / 9; int c = j2 - 9 * r; if (c > 7) c = 0;
      goff[it] = r * 4096 + c * 16;
    }
  }

  // Q fragments: 2 frags x 3 K-chunks, resident (scale pre-folded at RoPE)
  short8 aq[2][3];
#pragma unroll
  for (int f = 0; f < 2; f++) {
    const bf16* Qb = Qr + ((size_t)bh * SEQ + qbase + f * 64 + wave * 16 + l15) * HD + quad * 8;
    aq[f][0] = *(const short8*)(Qb);
    aq[f][1] = *(const short8*)(Qb + 32);
    aq[f][2] = *(const short8*)(Qb + 64);   // quad>=2 reads past row end (mapped)
    if (quad >= 2) aq[f][2] = (short8)0;    // exact zero pad d>=80
  }

  f32x4 o[2][6];      // [frag][5 data d-tiles + 1 denominator tile]
#pragma unroll
  for (int f = 0; f < 2; f++)
    for (int nt = 0; nt < 6; nt++) o[f][nt] = (f32x4)0.f;
  float m_i[2] = {-3e38f, -3e38f};   // per-lane row-max state for qrow=l15

  const char* Kb8 = (const char*)(Kr + (size_t)bh * SEQ * HD);
  const char* Vb8 = (const char*)(Vt + (size_t)bh * HD * SEQ);
  const int nsteps = 2 * qblk + 2;
  const int rmax0 = qbase + wave * 16 + 15;   // frag0 last row (frag1 always active)

  for (int step = 0; step < nsteps; step++) {
    const int kvo = step * 64;
    const bool act0 = (kvo <= rmax0);

    __syncthreads();   // prior step's LDS reads done (also covers ones-init)
    {
      const char* kb = Kb8 + kvo * 160;
      const char* vb = Vb8 + kvo * 2;
#pragma unroll
      for (int it = 0; it < 6; it++) {
        const int j = tid + it * 256;
        if (j < 1424) {
          bf16* ldsb = stage + (it * 256 + wave * 64) * 8;   // wave-uniform
          gld16((j < 704) ? (kb + goff[it]) : (vb + goff[it]), ldsb);
        }
      }
    }
    __syncthreads();   // staging landed

    // S^T = K Q^T : C-layout kv=quad*4+r (per tile), qrow=l15
    f32x4 sv[2][4];
#pragma unroll
    for (int nt = 0; nt < 4; nt++) {
      const bf16* kr = &kt[(nt * 16 + l15) * 88 + quad * 8];
      short8 b0 = *(const short8*)(kr);
      short8 b1 = *(const short8*)(kr + 32);
      short8 b2 = *(const short8*)(kr + 64);  // k>=80 garbage killed by aq[..][2]=0
      if (act0) {
        f32x4 s = mfma16(b0, aq[0][0], (f32x4)0.f);
        s = mfma16(b1, aq[0][1], s);
        sv[0][nt] = mfma16(b2, aq[0][2], s);
      }
      f32x4 s1 = mfma16(b0, aq[1][0], (f32x4)0.f);
      s1 = mfma16(b1, aq[1][1], s1);
      sv[1][nt] = mfma16(b2, aq[1][2], s1);
    }

    // online softmax per frag; per lane: 16 values of qrow=l15
#pragma unroll
    for (int f = 0; f < 2; f++) {
      if (f == 0 && !act0) continue;
      const int mrel = qbase + f * 64 + wave * 16 - kvo;   // wave-uniform
      if (mrel < 63) {
        const int qrel = mrel + l15;
#pragma unroll
        for (int nt = 0; nt < 4; nt++) {
          f32x4 t = sv[f][nt];
#pragma unroll
          for (int r = 0; r < 4; r++)
            t[r] = (nt * 16 + quad * 4 + r <= qrel) ? t[r] : -3e38f;
          sv[f][nt] = t;
        }
      }
      float mx = fmaxf(fmaxf(sv[f][0][0], sv[f][0][1]), fmaxf(sv[f][0][2], sv[f][0][3]));
#pragma unroll
      for (int nt = 1; nt < 4; nt++)
        mx = fmaxf(mx, fmaxf(fmaxf(sv[f][nt][0], sv[f][nt][1]),
                             fmaxf(sv[f][nt][2], sv[f][nt][3])));
      mx = fmaxf(mx, __shfl_xor(mx, 16, 64));
      mx = fmaxf(mx, __shfl_xor(mx, 32, 64));
      const float mnew = fmaxf(m_i[f], mx);
      const float alpha = __expf(m_i[f] - mnew);
      m_i[f] = mnew;

      bf16* ptw = pt + (wave * 2 + f) * 1152;
#pragma unroll
      for (int nt = 0; nt < 4; nt++) {
        __align__(8) bf16 p4[4];
#pragma unroll
        for (int r = 0; r < 4; r++) p4[r] = f2bf(__expf(sv[f][nt][r] - mnew));
        *(unsigned long long*)&ptw[l15 * 72 + nt * 16 + quad * 4] =
            *(const unsigned long long*)p4;
      }
      // broadcast alpha to O's C-layout rows (quad*4+r) via lanes 0..15
      float av[4];
#pragma unroll
      for (int r = 0; r < 4; r++) av[r] = __shfl(alpha, quad * 4 + r, 64);
#pragma unroll
      for (int nt = 0; nt < 6; nt++) {
        f32x4 t = o[f][nt];
        t[0] *= av[0]; t[1] *= av[1]; t[2] *= av[2]; t[3] *= av[3];
        o[f][nt] = t;
      }
    }

    asm volatile("s_waitcnt lgkmcnt(0)" ::: "memory");   // P^T writes landed (per-wave)
    short8 pa00 = (short8)0, pa01 = (short8)0, pa10, pa11;
    {
      const bf16* p0 = pt + (wave * 2 + 0) * 1152 + l15 * 72 + quad * 8;
      const bf16* p1 = pt + (wave * 2 + 1) * 1152 + l15 * 72 + quad * 8;
      if (act0) { pa00 = *(const short8*)p0; pa01 = *(const short8*)(p0 + 32); }
      pa10 = *(const short8*)p1; pa11 = *(const short8*)(p1 + 32);
    }
    // O += P V : 6 d-tiles (tile 5 = denominator), vt reads shared by frags
#pragma unroll
    for (int nt = 0; nt < 6; nt++) {
      const bf16* vr = &vt[(nt * 16 + l15) * 72 + quad * 8];
      short8 v0 = *(const short8*)(vr);
      short8 v1 = *(const short8*)(vr + 32);
      if (act0) {
        o[0][nt] = mfma16(pa00, v0, o[0][nt]);
        o[0][nt] = mfma16(pa01, v1, o[0][nt]);
      }
      o[1][nt] = mfma16(pa10, v0, o[1][nt]);
      o[1][nt] = mfma16(pa11, v1, o[1][nt]);
    }
  }

  // epilogue: out[t][h*80+d] = O / l
  const int b = bh >> 5, h = bh & 31;
#pragma unroll
  for (int f = 0; f < 2; f++)
#pragma unroll
    for (int r = 0; r < 4; r++) {
      const float inv = 1.0f / o[f][5][r];
      const int trow = b * SEQ + qbase + f * 64 + wave * 16 + quad * 4 + r;
#pragma unroll
      for (int nt = 0; nt < 5; nt++)
        O[(size_t)trow * HID + h * HD + nt * 16 + l15] = f2bf(o[f][nt][r] * inv);
    }
}

// ---------------------------------------------------------------------------
extern "C" void kernel_launch(void* const* d_in, const int* in_sizes, int n_in,
                              void* d_out, int out_size, void* d_ws, size_t ws_size,
                              hipStream_t stream) {
  (void)in_sizes; (void)n_in; (void)ws_size;
  char* wsb = (char*)d_ws;

  int*  flag   = (int*) (wsb + 0);
  bf16* cos_c  = (bf16*)(wsb + 1024);
  bf16* sin_c  = (bf16*)(wsb + 165888);
  bf16* bqkv_c = (bf16*)(wsb + 329728);
  bf16* bo_c   = (bf16*)(wsb + 345088);
  bf16* wo_c   = (bf16*)(wsb + 1048576);         // -> 14,155,776
  bf16* qkv    = (bf16*)(wsb + 14155776);        // -> 77,070,336
  bf16* hid_c  = (bf16*)(wsb + 77070336);        // -> 98,041,856
  bf16* wqkv_c = (bf16*)(wsb + 98041856);        // -> 137,363,456
  bf16* Qr     = (bf16*)(wsb + 77070336);        // over hid_c (dead post-GEMM1)
  bf16* Kr     = (bf16*)(wsb + 98041856);        // over wqkv_c (dead post-GEMM1)
  bf16* Vt     = (bf16*)(wsb + 119013376);       // -> 139,984,896
  bf16* attn   = (bf16*)(wsb + 14155776);        // over qkv (dead)
  bf16* obuf   = (bf16*)(wsb + 35127296);        // over qkv+21M

  detect_kernel<<<1, 256, 0, stream>>>((const unsigned short*)d_in[0], flag);
  convert_kernel<<<1024, 256, 0, stream>>>(d_in[0], hid_c,  TTOT * HID / 8, flag);
  convert_kernel<<<1024, 256, 0, stream>>>(d_in[1], wqkv_c, QKVN * HID / 8, flag);
  convert_kernel<<<4,    256, 0, stream>>>(d_in[2], bqkv_c, QKVN / 8,       flag);
  convert_kernel<<<1024, 256, 0, stream>>>(d_in[3], wo_c,   HID * HID / 8,  flag);
  convert_kernel<<<2,    256, 0, stream>>>(d_in[4], bo_c,   HID / 8,        flag);
  convert_kernel<<<40,   256, 0, stream>>>(d_in[5], cos_c,  TTOT * 20 / 8,  flag);
  convert_kernel<<<40,   256, 0, stream>>>(d_in[6], sin_c,  TTOT * 20 / 8,  flag);

  gemm256_bias<<<dim3((TTOT / 256) * (QKVN / 256)), 512, 0, stream>>>(
      hid_c, wqkv_c, bqkv_c, qkv, TTOT, QKVN, HID);
  rope_kernel<<<dim3(TTOT), 320, 0, stream>>>(qkv, cos_c, sin_c, Qr, Kr);
  vtrans_kernel<<<dim3(64, SEQ / 64), 256, 0, stream>>>(qkv, Vt);
  attn_kernel<<<dim3(1024), 256, 0, stream>>>(Qr, Kr, Vt, attn);
  gemm256_bias<<<dim3((TTOT / 256) * (HID / 256)), 512, 0, stream>>>(
      attn, wo_c, bo_c, obuf, TTOT, HID, HID);
  emit_kernel<<<1024, 256, 0, stream>>>(obuf, d_out, out_size / 8, flag);
}